// Round 8
// baseline (2790.836 us; speedup 1.0000x reference)
//
#include <hip/hip_runtime.h>
#include <math.h>

// ---------------------------------------------------------------------------
// MultiReferenceWindowAttention — bf16-MFMA GEMMs + bf16-LDS f32-math attention.
// B_=128, T=4, M=4, N=64, C=192, nH=6, hd=32, BT=512
// Workspace (<= proven 177,340,416 B):
//   qbuf f32  @ 0      (24 MB)  q -> later qq
//   xp  bf16  @ 24 MB  (48 MB)
//   kbuf bf16 @ 72 MB  (12 MB)  k -> later kk-chunk(bf16) -> later opo
//   vbuf bf16 @ 84 MB  (12 MB)  v
//   kk bf16 @ 72 MB (31.5 MB/chunk), vv bf16 @ 102 MB (31.5 MB/chunk)
// d_out doubles as opool scratch (fully rewritten by final GEMM).
// ---------------------------------------------------------------------------

typedef float f32x4 __attribute__((ext_vector_type(4)));
typedef short s16x8 __attribute__((ext_vector_type(8)));
typedef unsigned short u16x4 __attribute__((ext_vector_type(4)));
typedef unsigned short u16x8 __attribute__((ext_vector_type(8)));
typedef unsigned u32x4 __attribute__((ext_vector_type(4)));

__device__ __forceinline__ unsigned short f2bf(float f) {
    union { float f; unsigned u; } c; c.f = f;
    return (unsigned short)((c.u + 0x7fffu + ((c.u >> 16) & 1u)) >> 16);
}
__device__ __forceinline__ float bf2f(unsigned short h) {
    union { unsigned u; float f; } c; c.u = ((unsigned)h) << 16;
    return c.f;
}
__device__ __forceinline__ float bflo(unsigned w) {   // low bf16 of packed u32
    union { unsigned u; float f; } c; c.u = w << 16;
    return c.f;
}
__device__ __forceinline__ float bfhi(unsigned w) {   // high bf16 of packed u32
    union { unsigned u; float f; } c; c.u = w & 0xffff0000u;
    return c.f;
}

// ---------------------------------------------------------------------------
// MFMA bf16 GEMM:  C[row, oc] = sum_k Arow[k] * W[oc][k] + bias[oc]
// Block tile 128 rows x 96 oc, K=192 staged in 2 halves of 96.
// SRC: 0 = A plain f32 rows; 1 = mean_m xp(bf16) + pos; 2 = seq rows from xp.
// EPI: 0 plain, 1 exact gelu, 2 split oc@192 -> C0/C1 (b0 len 384),
//      3 split oc@192 -> C0 (W0,b0) / C1 (W1,b1)
// OUTBF: 0 = f32 out, 1 = bf16 out.
// ---------------------------------------------------------------------------
template <int SRC, int EPI, int OUTBF>
__global__ __launch_bounds__(256, 3)
void mgemm_kernel(const float* __restrict__ A, const unsigned short* __restrict__ Axp,
                  const float* __restrict__ pos,
                  const float* __restrict__ W0, const float* __restrict__ W1,
                  const float* __restrict__ b0, const float* __restrict__ b1,
                  void* __restrict__ C0v, void* __restrict__ C1v, int c0)
{
    __shared__ __align__(16) char As[128 * 192];   // 24 KB bf16 [row][k(96)]
    __shared__ __align__(16) char Bs[96 * 192];    // 18 KB bf16 [oc][k(96)]
    const int tid = threadIdx.x;
    const int gm0 = blockIdx.x * 128;
    const int gn0 = blockIdx.y * 96;
    const int wid = tid >> 6;
    const int wm = wid >> 1, wn = wid & 1;
    const int lane = tid & 63;
    const int lr = lane & 15;
    const int lk = lane >> 4;

    const bool hiN = (gn0 >= 192);
    const float* Wsel = (EPI == 3 && hiN) ? W1 : W0;
    const int wrow0 = (EPI == 3 && hiN) ? (gn0 - 192) : gn0;

    f32x4 acc[4][3];
#pragma unroll
    for (int i = 0; i < 4; i++)
#pragma unroll
        for (int j = 0; j < 3; j++) acc[i][j] = (f32x4){0.f, 0.f, 0.f, 0.f};

    for (int kb = 0; kb < 192; kb += 96) {
#pragma unroll
        for (int it = 0; it < 12; it++) {
            int f4 = tid + it * 256;
            int row = f4 / 24;
            int kc4 = (f4 - row * 24) * 4;
            float av[4];
            if (SRC == 0) {
                float4 v = *reinterpret_cast<const float4*>(
                    &A[(size_t)(gm0 + row) * 192 + kb + kc4]);
                av[0] = v.x; av[1] = v.y; av[2] = v.z; av[3] = v.w;
            } else {
                int g = gm0 + row;
                int bt, tok;
                if (SRC == 1) { bt = g >> 6; tok = g & 63; }
                else { bt = g / 320; tok = g - bt * 320; bt += c0; }
                int n = tok & 63;
                int kcol = kb + kc4;
                float4 p4 = *reinterpret_cast<const float4*>(&pos[n * 192 + kcol]);
                float pv[4] = {p4.x, p4.y, p4.z, p4.w};
                if (SRC == 2 && tok >= 64) {
                    int mm = (tok >> 6) - 1;
                    u16x4 a = *reinterpret_cast<const u16x4*>(
                        &Axp[(size_t)bt * 49152 + mm * 12288 + n * 192 + kcol]);
#pragma unroll
                    for (int jj = 0; jj < 4; jj++) av[jj] = bf2f(a[jj]) + pv[jj];
                } else {
                    size_t xb = (size_t)bt * 49152 + n * 192 + kcol;
                    u16x4 a0 = *reinterpret_cast<const u16x4*>(&Axp[xb]);
                    u16x4 a1 = *reinterpret_cast<const u16x4*>(&Axp[xb + 12288]);
                    u16x4 a2 = *reinterpret_cast<const u16x4*>(&Axp[xb + 24576]);
                    u16x4 a3 = *reinterpret_cast<const u16x4*>(&Axp[xb + 36864]);
#pragma unroll
                    for (int jj = 0; jj < 4; jj++)
                        av[jj] = 0.25f * (bf2f(a0[jj]) + bf2f(a1[jj]) +
                                          bf2f(a2[jj]) + bf2f(a3[jj])) + pv[jj];
                }
            }
            u16x4 bvv;
#pragma unroll
            for (int jj = 0; jj < 4; jj++) bvv[jj] = f2bf(av[jj]);
            int boff = (kc4 * 2) ^ ((row & 3) << 4);
            *reinterpret_cast<u16x4*>(As + row * 192 + boff) = bvv;
        }
#pragma unroll
        for (int it = 0; it < 9; it++) {
            int f4 = tid + it * 256;
            int row = f4 / 24;
            int kc4 = (f4 - row * 24) * 4;
            float4 v = *reinterpret_cast<const float4*>(
                &Wsel[(size_t)(wrow0 + row) * 192 + kb + kc4]);
            u16x4 bvv;
            bvv[0] = f2bf(v.x); bvv[1] = f2bf(v.y); bvv[2] = f2bf(v.z); bvv[3] = f2bf(v.w);
            int boff = (kc4 * 2) ^ ((row & 3) << 4);
            *reinterpret_cast<u16x4*>(Bs + row * 192 + boff) = bvv;
        }
        __syncthreads();

#pragma unroll
        for (int ks = 0; ks < 3; ks++) {
            s16x8 af[4], bf[3];
#pragma unroll
            for (int i = 0; i < 4; i++) {
                int row = wm * 64 + i * 16 + lr;
                int off = (ks * 64 + lk * 16) ^ ((row & 3) << 4);
                af[i] = *reinterpret_cast<const s16x8*>(As + row * 192 + off);
            }
#pragma unroll
            for (int j = 0; j < 3; j++) {
                int row = wn * 48 + j * 16 + lr;
                int off = (ks * 64 + lk * 16) ^ ((row & 3) << 4);
                bf[j] = *reinterpret_cast<const s16x8*>(Bs + row * 192 + off);
            }
#pragma unroll
            for (int i = 0; i < 4; i++)
#pragma unroll
                for (int j = 0; j < 3; j++)
                    acc[i][j] = __builtin_amdgcn_mfma_f32_16x16x32_bf16(
                        af[i], bf[j], acc[i][j], 0, 0, 0);
        }
        __syncthreads();
    }

#pragma unroll
    for (int j = 0; j < 3; j++) {
        int bcol = gn0 + wn * 48 + j * 16 + lr;
        float bv = (EPI == 3 && bcol >= 192) ? b1[bcol - 192] : b0[bcol];
        void* dst = C0v;
        int oc = bcol;
        if ((EPI == 2 || EPI == 3) && bcol >= 192) { dst = C1v; oc = bcol - 192; }
#pragma unroll
        for (int i = 0; i < 4; i++) {
            int rbase = gm0 + wm * 64 + i * 16 + lk * 4;
#pragma unroll
            for (int r = 0; r < 4; r++) {
                float v = acc[i][j][r] + bv;
                if (EPI == 1) v = 0.5f * v * (1.f + erff(v * 0.70710678118654752440f));
                size_t idx = (size_t)(rbase + r) * 192 + oc;
                if (OUTBF) ((unsigned short*)dst)[idx] = f2bf(v);
                else       ((float*)dst)[idx] = v;
            }
        }
    }
}

// ---------------------------------------------------------------------------
// Fused window attention, key-split, bf16 LDS: block = (bb,t,m), 768 thr = 12
// waves. Wave w: head h = w>>1, keys [(w&1)*32 .. +32). K/V/mask/rpb stored
// bf16 in one LDS pool (66.5 KB -> 2 blocks/CU); unpack in registers.
// obuf (pair-merge buffer) aliases the dead K/V region after PV.
// smem (u16 idx): K @0 [64*192], V @12288, mask @24576 [64*66],
//                 rpbT @28800 [6*226], exm(f32) @30160, exl(f32) @31696.
// ---------------------------------------------------------------------------
__global__ __launch_bounds__(768, 6)
void winattn_kernel(const float* __restrict__ qbuf,
                    const unsigned short* __restrict__ kbuf,
                    const unsigned short* __restrict__ vbuf,
                    const float* __restrict__ mask,
                    const float* __restrict__ rpbt, unsigned short* __restrict__ xp)
{
    __shared__ __align__(16) unsigned short smem[33232];   // 66464 B
    float* exm = (float*)(smem + 30160);
    float* exl = (float*)(smem + 31696);
    unsigned* obuf = (unsigned*)smem;                      // alias K/V after PV
    const int tid = threadIdx.x;
    const int bid = blockIdx.x;            // bb*16 + t*4 + m
    const int bb = bid >> 4;
    const int t = (bid >> 2) & 3;
    const int m = bid & 3;
    const int w = tid >> 6;
    const int h = w >> 1;
    const int lane = tid & 63;

    const int kvbase = (bb * 4 + m) * 12288;
#pragma unroll
    for (int it = 0; it < 2; it++) {
        int i8 = tid + it * 768;           // 0..1535
        *reinterpret_cast<u16x8*>(&smem[i8 * 8]) =
            *reinterpret_cast<const u16x8*>(&kbuf[kvbase + i8 * 8]);
        *reinterpret_cast<u16x8*>(&smem[12288 + i8 * 8]) =
            *reinterpret_cast<const u16x8*>(&vbuf[kvbase + i8 * 8]);
    }
    const int widx = bb & 63;
    for (int f = tid; f < 2048; f += 768) {
        int q = f >> 5, ee = (f & 31) * 2;
        float2 mv = *reinterpret_cast<const float2*>(&mask[widx * 4096 + q * 64 + ee]);
        unsigned pk = (unsigned)f2bf(mv.x) | ((unsigned)f2bf(mv.y) << 16);
        *reinterpret_cast<unsigned*>(&smem[24576 + q * 66 + ee]) = pk;
    }
    for (int f = tid; f < 1350; f += 768) {
        int hh = f / 225, rr = f - hh * 225;
        smem[28800 + hh * 226 + rr] = f2bf(rpbt[rr * 6 + hh]);
    }

    float qreg[32];
    const int qbase = ((bb * 4 + t) * 64 + lane) * 192 + h * 32;
#pragma unroll
    for (int j = 0; j < 8; j++) {
        float4 v = *reinterpret_cast<const float4*>(&qbuf[qbase + j * 4]);
        qreg[4 * j] = v.x; qreg[4 * j + 1] = v.y;
        qreg[4 * j + 2] = v.z; qreg[4 * j + 3] = v.w;
    }
    __syncthreads();

    const float scale = 0.17677669529663688110f;  // 1/sqrt(32)
    const int ni = lane >> 3, nj = lane & 7;
    const int e0 = (w & 1) << 5;
    float s[32];
#pragma unroll
    for (int ee = 0; ee < 32; ee++) {
        int e = e0 + ee;
        const u32x4* kr = reinterpret_cast<const u32x4*>(&smem[e * 192 + h * 32]);
        u32x4 k0 = kr[0], k1 = kr[1], k2 = kr[2], k3 = kr[3];
        float d0 = 0.f, d1 = 0.f;
        u32x4 kk[4] = {k0, k1, k2, k3};
#pragma unroll
        for (int v4 = 0; v4 < 4; v4++)
#pragma unroll
            for (int jj = 0; jj < 4; jj++) {
                unsigned wv = kk[v4][jj];
                int b = v4 * 8 + jj * 2;
                d0 += qreg[b] * bflo(wv);
                d1 += qreg[b + 1] * bfhi(wv);
            }
        int ridx = (ni - (e >> 3) + 7) * 15 + (nj - (e & 7) + 7);
        s[ee] = (d0 + d1) * scale + bf2f(smem[28800 + h * 226 + ridx])
              + bf2f(smem[24576 + lane * 66 + e]);
    }
    float mrun = s[0];
#pragma unroll
    for (int ee = 1; ee < 32; ee++) mrun = fmaxf(mrun, s[ee]);
    float lrun = 0.f;
#pragma unroll
    for (int ee = 0; ee < 32; ee++) { s[ee] = __expf(s[ee] - mrun); lrun += s[ee]; }

    float o[32];
#pragma unroll
    for (int d = 0; d < 32; d++) o[d] = 0.f;
#pragma unroll
    for (int ee = 0; ee < 32; ee++) {
        float p = s[ee];
        const u32x4* vr = reinterpret_cast<const u32x4*>(&smem[12288 + (e0 + ee) * 192 + h * 32]);
        u32x4 v0 = vr[0], v1 = vr[1], v2 = vr[2], v3 = vr[3];
        u32x4 vv[4] = {v0, v1, v2, v3};
#pragma unroll
        for (int v4 = 0; v4 < 4; v4++)
#pragma unroll
            for (int jj = 0; jj < 4; jj++) {
                unsigned wv = vv[v4][jj];
                int b = v4 * 8 + jj * 2;
                o[b] += p * bflo(wv);
                o[b + 1] += p * bfhi(wv);
            }
    }

    // ---- pair merge: waves (2h, 2h+1); obuf aliases dead K/V region ----
    __syncthreads();
    exm[w * 64 + lane] = mrun;
    __syncthreads();
    float mo = exm[(w ^ 1) * 64 + lane];
    float mt = fmaxf(mrun, mo);
    float fs = __expf(mrun - mt);
    if (w & 1) {
        unsigned* ob = &obuf[h * 1088 + lane * 17];
#pragma unroll
        for (int j = 0; j < 16; j++) {
            unsigned lo = f2bf(fs * o[2 * j]);
            unsigned hi = f2bf(fs * o[2 * j + 1]);
            ob[j] = lo | (hi << 16);
        }
        exl[w * 64 + lane] = fs * lrun;
    }
    __syncthreads();
    if (!(w & 1)) {
        float lt = fs * lrun + exl[(w + 1) * 64 + lane];
        const float inv = 1.f / lt;
        const unsigned* ob = &obuf[h * 1088 + lane * 17];
        const int obase = bb * 196608 + m * 49152 + t * 12288 + h * 2048 + lane * 32;
#pragma unroll
        for (int j = 0; j < 8; j++) {
            unsigned p0 = ob[2 * j], p1 = ob[2 * j + 1];
            u16x4 v;
            v[0] = f2bf((fs * o[4 * j]     + bf2f((unsigned short)(p0 & 0xffff))) * inv);
            v[1] = f2bf((fs * o[4 * j + 1] + bf2f((unsigned short)(p0 >> 16))) * inv);
            v[2] = f2bf((fs * o[4 * j + 2] + bf2f((unsigned short)(p1 & 0xffff))) * inv);
            v[3] = f2bf((fs * o[4 * j + 3] + bf2f((unsigned short)(p1 >> 16))) * inv);
            *reinterpret_cast<u16x4*>(&xp[obase + j * 4]) = v;
        }
    }
}

// ---------------------------------------------------------------------------
// Pooling attention: block = (h, btl), 320 threads = 5 waves.
// Wave w handles key tiles {w, w+5} of 10 (32 keys each), bf16 K/V in LDS.
// ---------------------------------------------------------------------------
__global__ __launch_bounds__(320)
void poolattn3_kernel(const unsigned short* __restrict__ kk,
                      const unsigned short* __restrict__ vv,
                      const float* __restrict__ qq, float* __restrict__ opool, int c0)
{
    __shared__ float ubuf[10560];      // bf16 K/V slots (20.5 KB) | merge o region
    __shared__ float scm[320], scl[320];
    const int tid = threadIdx.x;
    const int w = tid >> 6, lane = tid & 63;
    const int h = blockIdx.x, btl = blockIdx.y;
    const int bt = c0 + btl;
    unsigned short* Kw = (unsigned short*)ubuf + w * 2048;
    unsigned short* Vw = Kw + 1024;

    float qreg[32];
    const size_t qbase = (size_t)(bt * 64 + lane) * 192 + h * 32;
#pragma unroll
    for (int j = 0; j < 8; j++) {
        float4 v = *reinterpret_cast<const float4*>(&qq[qbase + j * 4]);
        qreg[4 * j] = v.x; qreg[4 * j + 1] = v.y;
        qreg[4 * j + 2] = v.z; qreg[4 * j + 3] = v.w;
    }
    const float scale = 0.17677669529663688110f;
    float mrun = -3.0e38f, lrun = 0.f;
    float o[32];
#pragma unroll
    for (int d = 0; d < 32; d++) o[d] = 0.f;

#pragma unroll
    for (int it = 0; it < 2; it++) {
        const int tt = w + it * 5;
        const unsigned short* ks = kk + (size_t)(btl * 320 + tt * 32) * 192 + h * 32;
        const unsigned short* vs = vv + (size_t)(btl * 320 + tt * 32) * 192 + h * 32;
#pragma unroll
        for (int ci = 0; ci < 2; ci++) {
            int i8 = lane + ci * 64;           // 0..127 -> tile flat [32][32] bf16
            int row = i8 >> 2, d8 = (i8 & 3) * 8;
            *reinterpret_cast<u16x8*>(&Kw[i8 * 8]) =
                *reinterpret_cast<const u16x8*>(&ks[row * 192 + d8]);
            *reinterpret_cast<u16x8*>(&Vw[i8 * 8]) =
                *reinterpret_cast<const u16x8*>(&vs[row * 192 + d8]);
        }
        float s[32];
#pragma unroll
        for (int j = 0; j < 32; j++) {
            const u32x4* kr = reinterpret_cast<const u32x4*>(Kw + j * 32);
            u32x4 k0 = kr[0], k1 = kr[1], k2 = kr[2], k3 = kr[3];
            u32x4 kv[4] = {k0, k1, k2, k3};
            float d0 = 0.f, d1 = 0.f;
#pragma unroll
            for (int v4 = 0; v4 < 4; v4++)
#pragma unroll
                for (int jj = 0; jj < 4; jj++) {
                    unsigned wv = kv[v4][jj];
                    int b = v4 * 8 + jj * 2;
                    d0 += qreg[b] * bflo(wv);
                    d1 += qreg[b + 1] * bfhi(wv);
                }
            s[j] = (d0 + d1) * scale;
        }
        float mt = s[0];
#pragma unroll
        for (int j = 1; j < 32; j++) mt = fmaxf(mt, s[j]);
        float mnew = fmaxf(mrun, mt);
        float fct = __expf(mrun - mnew);
        lrun *= fct;
#pragma unroll
        for (int d = 0; d < 32; d++) o[d] *= fct;
#pragma unroll
        for (int j = 0; j < 32; j++) { float p = __expf(s[j] - mnew); lrun += p; s[j] = p; }
#pragma unroll
        for (int j = 0; j < 32; j++) {
            float p = s[j];
            const u32x4* vr = reinterpret_cast<const u32x4*>(Vw + j * 32);
            u32x4 v0 = vr[0], v1 = vr[1], v2 = vr[2], v3 = vr[3];
            u32x4 vvv[4] = {v0, v1, v2, v3};
#pragma unroll
            for (int v4 = 0; v4 < 4; v4++)
#pragma unroll
                for (int jj = 0; jj < 4; jj++) {
                    unsigned wv = vvv[v4][jj];
                    int b = v4 * 8 + jj * 2;
                    o[b] += p * bflo(wv);
                    o[b + 1] += p * bfhi(wv);
                }
        }
        mrun = mnew;
    }
    __syncthreads();                 // everyone done with K/V region
    scm[w * 64 + lane] = mrun;
    scl[w * 64 + lane] = lrun;
#pragma unroll
    for (int d = 0; d < 32; d++) ubuf[w * 2112 + lane * 33 + d] = o[d];
    __syncthreads();

    if (w == 0) {
        float m5 = scm[lane];
#pragma unroll
        for (int ww = 1; ww < 5; ww++) m5 = fmaxf(m5, scm[ww * 64 + lane]);
        float den = 0.f;
        float od[32];
#pragma unroll
        for (int d = 0; d < 32; d++) od[d] = 0.f;
#pragma unroll
        for (int ww = 0; ww < 5; ww++) {
            float f = __expf(scm[ww * 64 + lane] - m5);
            den += f * scl[ww * 64 + lane];
            const float* src = ubuf + ww * 2112 + lane * 33;
#pragma unroll
            for (int d = 0; d < 32; d++) od[d] += f * src[d];
        }
        const float inv = 1.f / den;
        const size_t ob = (size_t)(bt * 64 + lane) * 192 + h * 32;
#pragma unroll
        for (int j = 0; j < 8; j++) {
            float4 v;
            v.x = od[4 * j] * inv; v.y = od[4 * j + 1] * inv;
            v.z = od[4 * j + 2] * inv; v.w = od[4 * j + 3] * inv;
            *reinterpret_cast<float4*>(&opool[ob + j * 4]) = v;
        }
    }
}

extern "C" void kernel_launch(void* const* d_in, const int* in_sizes, int n_in,
                              void* d_out, int out_size, void* d_ws, size_t ws_size,
                              hipStream_t stream) {
    (void)in_sizes; (void)n_in; (void)out_size; (void)ws_size;
    const float* x      = (const float*)d_in[0];
    const float* x_kv   = (const float*)d_in[1];
    const float* mask   = (const float*)d_in[2];
    const float* rpbt   = (const float*)d_in[3];
    const float* q_w    = (const float*)d_in[4];
    const float* q_b    = (const float*)d_in[5];
    const float* kv_w   = (const float*)d_in[6];
    const float* kv_b   = (const float*)d_in[7];
    const float* pos    = (const float*)d_in[8];
    const float* pq_w   = (const float*)d_in[9];
    const float* pq_b   = (const float*)d_in[10];
    const float* pk_w   = (const float*)d_in[11];
    const float* pk_b   = (const float*)d_in[12];
    const float* pv_w   = (const float*)d_in[13];
    const float* pv_b   = (const float*)d_in[14];
    const float* po_w   = (const float*)d_in[15];
    const float* po_b   = (const float*)d_in[16];
    const float* proj_w = (const float*)d_in[17];
    const float* proj_b = (const float*)d_in[18];
    float* out = (float*)d_out;
    char* ws = (char*)d_ws;

    float*          qbuf = (float*)(ws);                       // 24 MB
    unsigned short* xp   = (unsigned short*)(ws + 25165824u);  // 48 MB bf16
    unsigned short* kbuf = (unsigned short*)(ws + 75497472u);  // 12 MB bf16
    unsigned short* vbuf = (unsigned short*)(ws + 88080384u);  // 12 MB bf16
    float*          qq   = qbuf;
    unsigned short* kkc  = (unsigned short*)(ws + 75497472u);  // 31.5 MB / chunk
    unsigned short* vvc  = (unsigned short*)(ws + 106954752u); // 31.5 MB / chunk
    float*          opo  = (float*)(ws + 75497472u);           // after pooling
    float*          opool = out;                               // d_out as scratch

    dim3 blk(256);
    // q = x @ q_w^T + q_b
    mgemm_kernel<0, 0, 0><<<dim3(256, 2), blk, 0, stream>>>(
        x, nullptr, nullptr, q_w, nullptr, q_b, nullptr, qbuf, nullptr, 0);
    // k,v = x_kv @ kv_w^T + kv_b  (split at oc 192, bf16 out)
    mgemm_kernel<0, 2, 1><<<dim3(256, 4), blk, 0, stream>>>(
        x_kv, nullptr, nullptr, kv_w, nullptr, kv_b, nullptr, kbuf, vbuf, 0);
    winattn_kernel<<<2048, 768, 0, stream>>>(qbuf, kbuf, vbuf, mask, rpbt, xp);
    // qq = (mean_m xp + pos) @ pq_w^T + pq_b
    mgemm_kernel<1, 0, 0><<<dim3(256, 2), blk, 0, stream>>>(
        nullptr, xp, pos, pq_w, nullptr, pq_b, nullptr, qq, nullptr, 0);
    // pooling in 2 chunks of 256 bt
    for (int c0 = 0; c0 < 512; c0 += 256) {
        mgemm_kernel<2, 3, 1><<<dim3(640, 4), blk, 0, stream>>>(
            nullptr, xp, pos, pk_w, pv_w, pk_b, pv_b, kkc, vvc, c0);
        poolattn3_kernel<<<dim3(6, 256), 320, 0, stream>>>(kkc, vvc, qq, opool, c0);
    }
    // opo = gelu(opool @ po_w^T + po_b); out = opo @ proj_w^T + proj_b
    mgemm_kernel<0, 1, 0><<<dim3(256, 2), blk, 0, stream>>>(
        opool, nullptr, nullptr, po_w, nullptr, po_b, nullptr, opo, nullptr, 0);
    mgemm_kernel<0, 0, 0><<<dim3(256, 2), blk, 0, stream>>>(
        opo, nullptr, nullptr, proj_w, nullptr, proj_b, nullptr, out, nullptr, 0);
}

// Round 9
// 1865.866 us; speedup vs baseline: 1.4957x; 1.4957x over previous
//
#include <hip/hip_runtime.h>
#include <math.h>

// ---------------------------------------------------------------------------
// MultiReferenceWindowAttention — bf16-MFMA GEMMs + bf16-LDS f32-math attention.
// B_=128, T=4, M=4, N=64, C=192, nH=6, hd=32, BT=512
// Workspace (<= proven 177,340,416 B):
//   qbuf f32  @ 0      (24 MB)  q -> later qq
//   xp  bf16  @ 24 MB  (48 MB)
//   kbuf bf16 @ 72 MB  (12 MB)  k -> later kk-chunk(bf16) -> later opo
//   vbuf bf16 @ 84 MB  (12 MB)  v
//   kk bf16 @ 72 MB (31.5 MB/chunk), vv bf16 @ 102 MB (31.5 MB/chunk)
// d_out doubles as opool scratch (fully rewritten by final GEMM).
// NOTE (r8 lesson): winattn needs ~100 VGPR/lane (qreg+s+o); launch_bounds
// min-waves/EU > 3 forces spills (r8: VGPR 40, 5.6 GB scratch, 8.6x slower).
// ---------------------------------------------------------------------------

typedef float f32x4 __attribute__((ext_vector_type(4)));
typedef short s16x8 __attribute__((ext_vector_type(8)));
typedef unsigned short u16x4 __attribute__((ext_vector_type(4)));
typedef unsigned short u16x8 __attribute__((ext_vector_type(8)));
typedef unsigned u32x4 __attribute__((ext_vector_type(4)));

__device__ __forceinline__ unsigned short f2bf(float f) {
    union { float f; unsigned u; } c; c.f = f;
    return (unsigned short)((c.u + 0x7fffu + ((c.u >> 16) & 1u)) >> 16);
}
__device__ __forceinline__ float bf2f(unsigned short h) {
    union { unsigned u; float f; } c; c.u = ((unsigned)h) << 16;
    return c.f;
}
__device__ __forceinline__ float bflo(unsigned w) {   // low bf16 of packed u32
    union { unsigned u; float f; } c; c.u = w << 16;
    return c.f;
}
__device__ __forceinline__ float bfhi(unsigned w) {   // high bf16 of packed u32
    union { unsigned u; float f; } c; c.u = w & 0xffff0000u;
    return c.f;
}

// ---------------------------------------------------------------------------
// MFMA bf16 GEMM:  C[row, oc] = sum_k Arow[k] * W[oc][k] + bias[oc]
// Block tile 128 rows x 96 oc, K=192 staged in 2 halves of 96.
// SRC: 0 = A plain f32 rows; 1 = mean_m xp(bf16) + pos; 2 = seq rows from xp.
// EPI: 0 plain, 1 exact gelu, 2 split oc@192 -> C0/C1 (b0 len 384),
//      3 split oc@192 -> C0 (W0,b0) / C1 (W1,b1)
// OUTBF: 0 = f32 out, 1 = bf16 out.
// ---------------------------------------------------------------------------
template <int SRC, int EPI, int OUTBF>
__global__ __launch_bounds__(256, 3)
void mgemm_kernel(const float* __restrict__ A, const unsigned short* __restrict__ Axp,
                  const float* __restrict__ pos,
                  const float* __restrict__ W0, const float* __restrict__ W1,
                  const float* __restrict__ b0, const float* __restrict__ b1,
                  void* __restrict__ C0v, void* __restrict__ C1v, int c0)
{
    __shared__ __align__(16) char As[128 * 192];   // 24 KB bf16 [row][k(96)]
    __shared__ __align__(16) char Bs[96 * 192];    // 18 KB bf16 [oc][k(96)]
    const int tid = threadIdx.x;
    const int gm0 = blockIdx.x * 128;
    const int gn0 = blockIdx.y * 96;
    const int wid = tid >> 6;
    const int wm = wid >> 1, wn = wid & 1;
    const int lane = tid & 63;
    const int lr = lane & 15;
    const int lk = lane >> 4;

    const bool hiN = (gn0 >= 192);
    const float* Wsel = (EPI == 3 && hiN) ? W1 : W0;
    const int wrow0 = (EPI == 3 && hiN) ? (gn0 - 192) : gn0;

    f32x4 acc[4][3];
#pragma unroll
    for (int i = 0; i < 4; i++)
#pragma unroll
        for (int j = 0; j < 3; j++) acc[i][j] = (f32x4){0.f, 0.f, 0.f, 0.f};

    for (int kb = 0; kb < 192; kb += 96) {
#pragma unroll
        for (int it = 0; it < 12; it++) {
            int f4 = tid + it * 256;
            int row = f4 / 24;
            int kc4 = (f4 - row * 24) * 4;
            float av[4];
            if (SRC == 0) {
                float4 v = *reinterpret_cast<const float4*>(
                    &A[(size_t)(gm0 + row) * 192 + kb + kc4]);
                av[0] = v.x; av[1] = v.y; av[2] = v.z; av[3] = v.w;
            } else {
                int g = gm0 + row;
                int bt, tok;
                if (SRC == 1) { bt = g >> 6; tok = g & 63; }
                else { bt = g / 320; tok = g - bt * 320; bt += c0; }
                int n = tok & 63;
                int kcol = kb + kc4;
                float4 p4 = *reinterpret_cast<const float4*>(&pos[n * 192 + kcol]);
                float pv[4] = {p4.x, p4.y, p4.z, p4.w};
                if (SRC == 2 && tok >= 64) {
                    int mm = (tok >> 6) - 1;
                    u16x4 a = *reinterpret_cast<const u16x4*>(
                        &Axp[(size_t)bt * 49152 + mm * 12288 + n * 192 + kcol]);
#pragma unroll
                    for (int jj = 0; jj < 4; jj++) av[jj] = bf2f(a[jj]) + pv[jj];
                } else {
                    size_t xb = (size_t)bt * 49152 + n * 192 + kcol;
                    u16x4 a0 = *reinterpret_cast<const u16x4*>(&Axp[xb]);
                    u16x4 a1 = *reinterpret_cast<const u16x4*>(&Axp[xb + 12288]);
                    u16x4 a2 = *reinterpret_cast<const u16x4*>(&Axp[xb + 24576]);
                    u16x4 a3 = *reinterpret_cast<const u16x4*>(&Axp[xb + 36864]);
#pragma unroll
                    for (int jj = 0; jj < 4; jj++)
                        av[jj] = 0.25f * (bf2f(a0[jj]) + bf2f(a1[jj]) +
                                          bf2f(a2[jj]) + bf2f(a3[jj])) + pv[jj];
                }
            }
            u16x4 bvv;
#pragma unroll
            for (int jj = 0; jj < 4; jj++) bvv[jj] = f2bf(av[jj]);
            int boff = (kc4 * 2) ^ ((row & 3) << 4);
            *reinterpret_cast<u16x4*>(As + row * 192 + boff) = bvv;
        }
#pragma unroll
        for (int it = 0; it < 9; it++) {
            int f4 = tid + it * 256;
            int row = f4 / 24;
            int kc4 = (f4 - row * 24) * 4;
            float4 v = *reinterpret_cast<const float4*>(
                &Wsel[(size_t)(wrow0 + row) * 192 + kb + kc4]);
            u16x4 bvv;
            bvv[0] = f2bf(v.x); bvv[1] = f2bf(v.y); bvv[2] = f2bf(v.z); bvv[3] = f2bf(v.w);
            int boff = (kc4 * 2) ^ ((row & 3) << 4);
            *reinterpret_cast<u16x4*>(Bs + row * 192 + boff) = bvv;
        }
        __syncthreads();

#pragma unroll
        for (int ks = 0; ks < 3; ks++) {
            s16x8 af[4], bf[3];
#pragma unroll
            for (int i = 0; i < 4; i++) {
                int row = wm * 64 + i * 16 + lr;
                int off = (ks * 64 + lk * 16) ^ ((row & 3) << 4);
                af[i] = *reinterpret_cast<const s16x8*>(As + row * 192 + off);
            }
#pragma unroll
            for (int j = 0; j < 3; j++) {
                int row = wn * 48 + j * 16 + lr;
                int off = (ks * 64 + lk * 16) ^ ((row & 3) << 4);
                bf[j] = *reinterpret_cast<const s16x8*>(Bs + row * 192 + off);
            }
#pragma unroll
            for (int i = 0; i < 4; i++)
#pragma unroll
                for (int j = 0; j < 3; j++)
                    acc[i][j] = __builtin_amdgcn_mfma_f32_16x16x32_bf16(
                        af[i], bf[j], acc[i][j], 0, 0, 0);
        }
        __syncthreads();
    }

#pragma unroll
    for (int j = 0; j < 3; j++) {
        int bcol = gn0 + wn * 48 + j * 16 + lr;
        float bv = (EPI == 3 && bcol >= 192) ? b1[bcol - 192] : b0[bcol];
        void* dst = C0v;
        int oc = bcol;
        if ((EPI == 2 || EPI == 3) && bcol >= 192) { dst = C1v; oc = bcol - 192; }
#pragma unroll
        for (int i = 0; i < 4; i++) {
            int rbase = gm0 + wm * 64 + i * 16 + lk * 4;
#pragma unroll
            for (int r = 0; r < 4; r++) {
                float v = acc[i][j][r] + bv;
                if (EPI == 1) v = 0.5f * v * (1.f + erff(v * 0.70710678118654752440f));
                size_t idx = (size_t)(rbase + r) * 192 + oc;
                if (OUTBF) ((unsigned short*)dst)[idx] = f2bf(v);
                else       ((float*)dst)[idx] = v;
            }
        }
    }
}

// ---------------------------------------------------------------------------
// Fused window attention, key-split, bf16 LDS: block = (bb,t,m), 768 thr = 12
// waves. Wave w: head h = w>>1, keys [(w&1)*32 .. +32). K/V/mask/rpb stored
// bf16 in one LDS pool (66.5 KB); unpack in registers.
// launch_bounds min-waves = 3 (1 block/CU): >3 forces VGPR spills (r8).
// smem (u16 idx): K @0 [64*192], V @12288, mask @24576 [64*66],
//                 rpbT @28800 [6*226], exm(f32) @30160, exl(f32) @31696.
// ---------------------------------------------------------------------------
__global__ __launch_bounds__(768, 3)
void winattn_kernel(const float* __restrict__ qbuf,
                    const unsigned short* __restrict__ kbuf,
                    const unsigned short* __restrict__ vbuf,
                    const float* __restrict__ mask,
                    const float* __restrict__ rpbt, unsigned short* __restrict__ xp)
{
    __shared__ __align__(16) unsigned short smem[33232];   // 66464 B
    float* exm = (float*)(smem + 30160);
    float* exl = (float*)(smem + 31696);
    unsigned* obuf = (unsigned*)smem;                      // alias K/V after PV
    const int tid = threadIdx.x;
    const int bid = blockIdx.x;            // bb*16 + t*4 + m
    const int bb = bid >> 4;
    const int t = (bid >> 2) & 3;
    const int m = bid & 3;
    const int w = tid >> 6;
    const int h = w >> 1;
    const int lane = tid & 63;

    const int kvbase = (bb * 4 + m) * 12288;
#pragma unroll
    for (int it = 0; it < 2; it++) {
        int i8 = tid + it * 768;           // 0..1535
        *reinterpret_cast<u16x8*>(&smem[i8 * 8]) =
            *reinterpret_cast<const u16x8*>(&kbuf[kvbase + i8 * 8]);
        *reinterpret_cast<u16x8*>(&smem[12288 + i8 * 8]) =
            *reinterpret_cast<const u16x8*>(&vbuf[kvbase + i8 * 8]);
    }
    const int widx = bb & 63;
    for (int f = tid; f < 2048; f += 768) {
        int q = f >> 5, ee = (f & 31) * 2;
        float2 mv = *reinterpret_cast<const float2*>(&mask[widx * 4096 + q * 64 + ee]);
        unsigned pk = (unsigned)f2bf(mv.x) | ((unsigned)f2bf(mv.y) << 16);
        *reinterpret_cast<unsigned*>(&smem[24576 + q * 66 + ee]) = pk;
    }
    for (int f = tid; f < 1350; f += 768) {
        int hh = f / 225, rr = f - hh * 225;
        smem[28800 + hh * 226 + rr] = f2bf(rpbt[rr * 6 + hh]);
    }

    float qreg[32];
    const int qbase = ((bb * 4 + t) * 64 + lane) * 192 + h * 32;
#pragma unroll
    for (int j = 0; j < 8; j++) {
        float4 v = *reinterpret_cast<const float4*>(&qbuf[qbase + j * 4]);
        qreg[4 * j] = v.x; qreg[4 * j + 1] = v.y;
        qreg[4 * j + 2] = v.z; qreg[4 * j + 3] = v.w;
    }
    __syncthreads();

    const float scale = 0.17677669529663688110f;  // 1/sqrt(32)
    const int ni = lane >> 3, nj = lane & 7;
    const int e0 = (w & 1) << 5;
    float s[32];
#pragma unroll
    for (int ee = 0; ee < 32; ee++) {
        int e = e0 + ee;
        const u32x4* kr = reinterpret_cast<const u32x4*>(&smem[e * 192 + h * 32]);
        u32x4 k0 = kr[0], k1 = kr[1], k2 = kr[2], k3 = kr[3];
        float d0 = 0.f, d1 = 0.f;
        u32x4 kk[4] = {k0, k1, k2, k3};
#pragma unroll
        for (int v4 = 0; v4 < 4; v4++)
#pragma unroll
            for (int jj = 0; jj < 4; jj++) {
                unsigned wv = kk[v4][jj];
                int b = v4 * 8 + jj * 2;
                d0 += qreg[b] * bflo(wv);
                d1 += qreg[b + 1] * bfhi(wv);
            }
        int ridx = (ni - (e >> 3) + 7) * 15 + (nj - (e & 7) + 7);
        s[ee] = (d0 + d1) * scale + bf2f(smem[28800 + h * 226 + ridx])
              + bf2f(smem[24576 + lane * 66 + e]);
    }
    float mrun = s[0];
#pragma unroll
    for (int ee = 1; ee < 32; ee++) mrun = fmaxf(mrun, s[ee]);
    float lrun = 0.f;
#pragma unroll
    for (int ee = 0; ee < 32; ee++) { s[ee] = __expf(s[ee] - mrun); lrun += s[ee]; }

    float o[32];
#pragma unroll
    for (int d = 0; d < 32; d++) o[d] = 0.f;
#pragma unroll
    for (int ee = 0; ee < 32; ee++) {
        float p = s[ee];
        const u32x4* vr = reinterpret_cast<const u32x4*>(&smem[12288 + (e0 + ee) * 192 + h * 32]);
        u32x4 v0 = vr[0], v1 = vr[1], v2 = vr[2], v3 = vr[3];
        u32x4 vv[4] = {v0, v1, v2, v3};
#pragma unroll
        for (int v4 = 0; v4 < 4; v4++)
#pragma unroll
            for (int jj = 0; jj < 4; jj++) {
                unsigned wv = vv[v4][jj];
                int b = v4 * 8 + jj * 2;
                o[b] += p * bflo(wv);
                o[b + 1] += p * bfhi(wv);
            }
    }

    // ---- pair merge: waves (2h, 2h+1); obuf aliases dead K/V region ----
    __syncthreads();
    exm[w * 64 + lane] = mrun;
    __syncthreads();
    float mo = exm[(w ^ 1) * 64 + lane];
    float mt = fmaxf(mrun, mo);
    float fs = __expf(mrun - mt);
    if (w & 1) {
        unsigned* ob = &obuf[h * 1088 + lane * 17];
#pragma unroll
        for (int j = 0; j < 16; j++) {
            unsigned lo = f2bf(fs * o[2 * j]);
            unsigned hi = f2bf(fs * o[2 * j + 1]);
            ob[j] = lo | (hi << 16);
        }
        exl[w * 64 + lane] = fs * lrun;
    }
    __syncthreads();
    if (!(w & 1)) {
        float lt = fs * lrun + exl[(w + 1) * 64 + lane];
        const float inv = 1.f / lt;
        const unsigned* ob = &obuf[h * 1088 + lane * 17];
        const int obase = bb * 196608 + m * 49152 + t * 12288 + h * 2048 + lane * 32;
#pragma unroll
        for (int j = 0; j < 8; j++) {
            unsigned p0 = ob[2 * j], p1 = ob[2 * j + 1];
            u16x4 v;
            v[0] = f2bf((fs * o[4 * j]     + bf2f((unsigned short)(p0 & 0xffff))) * inv);
            v[1] = f2bf((fs * o[4 * j + 1] + bf2f((unsigned short)(p0 >> 16))) * inv);
            v[2] = f2bf((fs * o[4 * j + 2] + bf2f((unsigned short)(p1 & 0xffff))) * inv);
            v[3] = f2bf((fs * o[4 * j + 3] + bf2f((unsigned short)(p1 >> 16))) * inv);
            *reinterpret_cast<u16x4*>(&xp[obase + j * 4]) = v;
        }
    }
}

// ---------------------------------------------------------------------------
// Pooling attention: block = (h, btl), 320 threads = 5 waves.
// Wave w handles key tiles {w, w+5} of 10 (32 keys each), bf16 K/V in LDS.
// ---------------------------------------------------------------------------
__global__ __launch_bounds__(320)
void poolattn3_kernel(const unsigned short* __restrict__ kk,
                      const unsigned short* __restrict__ vv,
                      const float* __restrict__ qq, float* __restrict__ opool, int c0)
{
    __shared__ float ubuf[10560];      // bf16 K/V slots (20.5 KB) | merge o region
    __shared__ float scm[320], scl[320];
    const int tid = threadIdx.x;
    const int w = tid >> 6, lane = tid & 63;
    const int h = blockIdx.x, btl = blockIdx.y;
    const int bt = c0 + btl;
    unsigned short* Kw = (unsigned short*)ubuf + w * 2048;
    unsigned short* Vw = Kw + 1024;

    float qreg[32];
    const size_t qbase = (size_t)(bt * 64 + lane) * 192 + h * 32;
#pragma unroll
    for (int j = 0; j < 8; j++) {
        float4 v = *reinterpret_cast<const float4*>(&qq[qbase + j * 4]);
        qreg[4 * j] = v.x; qreg[4 * j + 1] = v.y;
        qreg[4 * j + 2] = v.z; qreg[4 * j + 3] = v.w;
    }
    const float scale = 0.17677669529663688110f;
    float mrun = -3.0e38f, lrun = 0.f;
    float o[32];
#pragma unroll
    for (int d = 0; d < 32; d++) o[d] = 0.f;

#pragma unroll
    for (int it = 0; it < 2; it++) {
        const int tt = w + it * 5;
        const unsigned short* ks = kk + (size_t)(btl * 320 + tt * 32) * 192 + h * 32;
        const unsigned short* vs = vv + (size_t)(btl * 320 + tt * 32) * 192 + h * 32;
#pragma unroll
        for (int ci = 0; ci < 2; ci++) {
            int i8 = lane + ci * 64;           // 0..127 -> tile flat [32][32] bf16
            int row = i8 >> 2, d8 = (i8 & 3) * 8;
            *reinterpret_cast<u16x8*>(&Kw[i8 * 8]) =
                *reinterpret_cast<const u16x8*>(&ks[row * 192 + d8]);
            *reinterpret_cast<u16x8*>(&Vw[i8 * 8]) =
                *reinterpret_cast<const u16x8*>(&vs[row * 192 + d8]);
        }
        float s[32];
#pragma unroll
        for (int j = 0; j < 32; j++) {
            const u32x4* kr = reinterpret_cast<const u32x4*>(Kw + j * 32);
            u32x4 k0 = kr[0], k1 = kr[1], k2 = kr[2], k3 = kr[3];
            u32x4 kv[4] = {k0, k1, k2, k3};
            float d0 = 0.f, d1 = 0.f;
#pragma unroll
            for (int v4 = 0; v4 < 4; v4++)
#pragma unroll
                for (int jj = 0; jj < 4; jj++) {
                    unsigned wv = kv[v4][jj];
                    int b = v4 * 8 + jj * 2;
                    d0 += qreg[b] * bflo(wv);
                    d1 += qreg[b + 1] * bfhi(wv);
                }
            s[j] = (d0 + d1) * scale;
        }
        float mt = s[0];
#pragma unroll
        for (int j = 1; j < 32; j++) mt = fmaxf(mt, s[j]);
        float mnew = fmaxf(mrun, mt);
        float fct = __expf(mrun - mnew);
        lrun *= fct;
#pragma unroll
        for (int d = 0; d < 32; d++) o[d] *= fct;
#pragma unroll
        for (int j = 0; j < 32; j++) { float p = __expf(s[j] - mnew); lrun += p; s[j] = p; }
#pragma unroll
        for (int j = 0; j < 32; j++) {
            float p = s[j];
            const u32x4* vr = reinterpret_cast<const u32x4*>(Vw + j * 32);
            u32x4 v0 = vr[0], v1 = vr[1], v2 = vr[2], v3 = vr[3];
            u32x4 vvv[4] = {v0, v1, v2, v3};
#pragma unroll
            for (int v4 = 0; v4 < 4; v4++)
#pragma unroll
                for (int jj = 0; jj < 4; jj++) {
                    unsigned wv = vvv[v4][jj];
                    int b = v4 * 8 + jj * 2;
                    o[b] += p * bflo(wv);
                    o[b + 1] += p * bfhi(wv);
                }
        }
        mrun = mnew;
    }
    __syncthreads();                 // everyone done with K/V region
    scm[w * 64 + lane] = mrun;
    scl[w * 64 + lane] = lrun;
#pragma unroll
    for (int d = 0; d < 32; d++) ubuf[w * 2112 + lane * 33 + d] = o[d];
    __syncthreads();

    if (w == 0) {
        float m5 = scm[lane];
#pragma unroll
        for (int ww = 1; ww < 5; ww++) m5 = fmaxf(m5, scm[ww * 64 + lane]);
        float den = 0.f;
        float od[32];
#pragma unroll
        for (int d = 0; d < 32; d++) od[d] = 0.f;
#pragma unroll
        for (int ww = 0; ww < 5; ww++) {
            float f = __expf(scm[ww * 64 + lane] - m5);
            den += f * scl[ww * 64 + lane];
            const float* src = ubuf + ww * 2112 + lane * 33;
#pragma unroll
            for (int d = 0; d < 32; d++) od[d] += f * src[d];
        }
        const float inv = 1.f / den;
        const size_t ob = (size_t)(bt * 64 + lane) * 192 + h * 32;
#pragma unroll
        for (int j = 0; j < 8; j++) {
            float4 v;
            v.x = od[4 * j] * inv; v.y = od[4 * j + 1] * inv;
            v.z = od[4 * j + 2] * inv; v.w = od[4 * j + 3] * inv;
            *reinterpret_cast<float4*>(&opool[ob + j * 4]) = v;
        }
    }
}

extern "C" void kernel_launch(void* const* d_in, const int* in_sizes, int n_in,
                              void* d_out, int out_size, void* d_ws, size_t ws_size,
                              hipStream_t stream) {
    (void)in_sizes; (void)n_in; (void)out_size; (void)ws_size;
    const float* x      = (const float*)d_in[0];
    const float* x_kv   = (const float*)d_in[1];
    const float* mask   = (const float*)d_in[2];
    const float* rpbt   = (const float*)d_in[3];
    const float* q_w    = (const float*)d_in[4];
    const float* q_b    = (const float*)d_in[5];
    const float* kv_w   = (const float*)d_in[6];
    const float* kv_b   = (const float*)d_in[7];
    const float* pos    = (const float*)d_in[8];
    const float* pq_w   = (const float*)d_in[9];
    const float* pq_b   = (const float*)d_in[10];
    const float* pk_w   = (const float*)d_in[11];
    const float* pk_b   = (const float*)d_in[12];
    const float* pv_w   = (const float*)d_in[13];
    const float* pv_b   = (const float*)d_in[14];
    const float* po_w   = (const float*)d_in[15];
    const float* po_b   = (const float*)d_in[16];
    const float* proj_w = (const float*)d_in[17];
    const float* proj_b = (const float*)d_in[18];
    float* out = (float*)d_out;
    char* ws = (char*)d_ws;

    float*          qbuf = (float*)(ws);                       // 24 MB
    unsigned short* xp   = (unsigned short*)(ws + 25165824u);  // 48 MB bf16
    unsigned short* kbuf = (unsigned short*)(ws + 75497472u);  // 12 MB bf16
    unsigned short* vbuf = (unsigned short*)(ws + 88080384u);  // 12 MB bf16
    float*          qq   = qbuf;
    unsigned short* kkc  = (unsigned short*)(ws + 75497472u);  // 31.5 MB / chunk
    unsigned short* vvc  = (unsigned short*)(ws + 106954752u); // 31.5 MB / chunk
    float*          opo  = (float*)(ws + 75497472u);           // after pooling
    float*          opool = out;                               // d_out as scratch

    dim3 blk(256);
    // q = x @ q_w^T + q_b
    mgemm_kernel<0, 0, 0><<<dim3(256, 2), blk, 0, stream>>>(
        x, nullptr, nullptr, q_w, nullptr, q_b, nullptr, qbuf, nullptr, 0);
    // k,v = x_kv @ kv_w^T + kv_b  (split at oc 192, bf16 out)
    mgemm_kernel<0, 2, 1><<<dim3(256, 4), blk, 0, stream>>>(
        x_kv, nullptr, nullptr, kv_w, nullptr, kv_b, nullptr, kbuf, vbuf, 0);
    winattn_kernel<<<2048, 768, 0, stream>>>(qbuf, kbuf, vbuf, mask, rpbt, xp);
    // qq = (mean_m xp + pos) @ pq_w^T + pq_b
    mgemm_kernel<1, 0, 0><<<dim3(256, 2), blk, 0, stream>>>(
        nullptr, xp, pos, pq_w, nullptr, pq_b, nullptr, qq, nullptr, 0);
    // pooling in 2 chunks of 256 bt
    for (int c0 = 0; c0 < 512; c0 += 256) {
        mgemm_kernel<2, 3, 1><<<dim3(640, 4), blk, 0, stream>>>(
            nullptr, xp, pos, pk_w, pv_w, pk_b, pv_b, kkc, vvc, c0);
        poolattn3_kernel<<<dim3(6, 256), 320, 0, stream>>>(kkc, vvc, qq, opool, c0);
    }
    // opo = gelu(opool @ po_w^T + po_b); out = opo @ proj_w^T + proj_b
    mgemm_kernel<0, 1, 0><<<dim3(256, 2), blk, 0, stream>>>(
        opool, nullptr, nullptr, po_w, nullptr, po_b, nullptr, opo, nullptr, 0);
    mgemm_kernel<0, 0, 0><<<dim3(256, 2), blk, 0, stream>>>(
        opo, nullptr, nullptr, proj_w, nullptr, proj_b, nullptr, out, nullptr, 0);
}

// Round 10
// 1349.198 us; speedup vs baseline: 2.0685x; 1.3829x over previous
//
#include <hip/hip_runtime.h>
#include <math.h>

// ---------------------------------------------------------------------------
// MultiReferenceWindowAttention — bf16-MFMA GEMMs + attention.
// B_=128, T=4, M=4, N=64, C=192, nH=6, hd=32, BT=512
// Workspace (<= proven 177,340,416 B):
//   qbuf f32  @ 0      (24 MB)  q -> later qq
//   xp  bf16  @ 24 MB  (48 MB)
//   kbuf bf16 @ 72 MB  (12 MB)  k -> later kk-chunk(bf16) -> later opo
//   vbuf bf16 @ 84 MB  (12 MB)  v
//   kk bf16 @ 72 MB (31.5 MB/chunk), vv bf16 @ 102 MB (31.5 MB/chunk)
// d_out doubles as opool scratch (fully rewritten by final GEMM).
// VGPR lesson (r8/r9): these attention kernels need ~110 VGPR/lane
// (qreg32+s32+o32+temps). __launch_bounds__ min-waves >= 2 caps VGPR at
// <=84 and forces scratch spills (r8: 5.6 GB, r9: 2.9 GB traffic).
// Only (768,1) is proven spill-free (r7: VGPR 80, WRITE 49 MB).
// ---------------------------------------------------------------------------

typedef float f32x4 __attribute__((ext_vector_type(4)));
typedef short s16x8 __attribute__((ext_vector_type(8)));
typedef unsigned short u16x4 __attribute__((ext_vector_type(4)));
typedef unsigned short u16x8 __attribute__((ext_vector_type(8)));
typedef unsigned u32x4 __attribute__((ext_vector_type(4)));

__device__ __forceinline__ unsigned short f2bf(float f) {
    union { float f; unsigned u; } c; c.f = f;
    return (unsigned short)((c.u + 0x7fffu + ((c.u >> 16) & 1u)) >> 16);
}
__device__ __forceinline__ float bf2f(unsigned short h) {
    union { unsigned u; float f; } c; c.u = ((unsigned)h) << 16;
    return c.f;
}
__device__ __forceinline__ float bflo(unsigned w) {   // low bf16 of packed u32
    union { unsigned u; float f; } c; c.u = w << 16;
    return c.f;
}
__device__ __forceinline__ float bfhi(unsigned w) {   // high bf16 of packed u32
    union { unsigned u; float f; } c; c.u = w & 0xffff0000u;
    return c.f;
}

// ---------------------------------------------------------------------------
// MFMA bf16 GEMM:  C[row, oc] = sum_k Arow[k] * W[oc][k] + bias[oc]
// Block tile 128 rows x 96 oc, K=192 staged in 2 halves of 96.
// SRC: 0 = A plain f32 rows; 1 = mean_m xp(bf16) + pos; 2 = seq rows from xp.
// EPI: 0 plain, 1 exact gelu, 2 split oc@192 -> C0/C1 (b0 len 384),
//      3 split oc@192 -> C0 (W0,b0) / C1 (W1,b1)
// OUTBF: 0 = f32 out, 1 = bf16 out.
// ---------------------------------------------------------------------------
template <int SRC, int EPI, int OUTBF>
__global__ __launch_bounds__(256, 3)
void mgemm_kernel(const float* __restrict__ A, const unsigned short* __restrict__ Axp,
                  const float* __restrict__ pos,
                  const float* __restrict__ W0, const float* __restrict__ W1,
                  const float* __restrict__ b0, const float* __restrict__ b1,
                  void* __restrict__ C0v, void* __restrict__ C1v, int c0)
{
    __shared__ __align__(16) char As[128 * 192];   // 24 KB bf16 [row][k(96)]
    __shared__ __align__(16) char Bs[96 * 192];    // 18 KB bf16 [oc][k(96)]
    const int tid = threadIdx.x;
    const int gm0 = blockIdx.x * 128;
    const int gn0 = blockIdx.y * 96;
    const int wid = tid >> 6;
    const int wm = wid >> 1, wn = wid & 1;
    const int lane = tid & 63;
    const int lr = lane & 15;
    const int lk = lane >> 4;

    const bool hiN = (gn0 >= 192);
    const float* Wsel = (EPI == 3 && hiN) ? W1 : W0;
    const int wrow0 = (EPI == 3 && hiN) ? (gn0 - 192) : gn0;

    f32x4 acc[4][3];
#pragma unroll
    for (int i = 0; i < 4; i++)
#pragma unroll
        for (int j = 0; j < 3; j++) acc[i][j] = (f32x4){0.f, 0.f, 0.f, 0.f};

    for (int kb = 0; kb < 192; kb += 96) {
#pragma unroll
        for (int it = 0; it < 12; it++) {
            int f4 = tid + it * 256;
            int row = f4 / 24;
            int kc4 = (f4 - row * 24) * 4;
            float av[4];
            if (SRC == 0) {
                float4 v = *reinterpret_cast<const float4*>(
                    &A[(size_t)(gm0 + row) * 192 + kb + kc4]);
                av[0] = v.x; av[1] = v.y; av[2] = v.z; av[3] = v.w;
            } else {
                int g = gm0 + row;
                int bt, tok;
                if (SRC == 1) { bt = g >> 6; tok = g & 63; }
                else { bt = g / 320; tok = g - bt * 320; bt += c0; }
                int n = tok & 63;
                int kcol = kb + kc4;
                float4 p4 = *reinterpret_cast<const float4*>(&pos[n * 192 + kcol]);
                float pv[4] = {p4.x, p4.y, p4.z, p4.w};
                if (SRC == 2 && tok >= 64) {
                    int mm = (tok >> 6) - 1;
                    u16x4 a = *reinterpret_cast<const u16x4*>(
                        &Axp[(size_t)bt * 49152 + mm * 12288 + n * 192 + kcol]);
#pragma unroll
                    for (int jj = 0; jj < 4; jj++) av[jj] = bf2f(a[jj]) + pv[jj];
                } else {
                    size_t xb = (size_t)bt * 49152 + n * 192 + kcol;
                    u16x4 a0 = *reinterpret_cast<const u16x4*>(&Axp[xb]);
                    u16x4 a1 = *reinterpret_cast<const u16x4*>(&Axp[xb + 12288]);
                    u16x4 a2 = *reinterpret_cast<const u16x4*>(&Axp[xb + 24576]);
                    u16x4 a3 = *reinterpret_cast<const u16x4*>(&Axp[xb + 36864]);
#pragma unroll
                    for (int jj = 0; jj < 4; jj++)
                        av[jj] = 0.25f * (bf2f(a0[jj]) + bf2f(a1[jj]) +
                                          bf2f(a2[jj]) + bf2f(a3[jj])) + pv[jj];
                }
            }
            u16x4 bvv;
#pragma unroll
            for (int jj = 0; jj < 4; jj++) bvv[jj] = f2bf(av[jj]);
            int boff = (kc4 * 2) ^ ((row & 3) << 4);
            *reinterpret_cast<u16x4*>(As + row * 192 + boff) = bvv;
        }
#pragma unroll
        for (int it = 0; it < 9; it++) {
            int f4 = tid + it * 256;
            int row = f4 / 24;
            int kc4 = (f4 - row * 24) * 4;
            float4 v = *reinterpret_cast<const float4*>(
                &Wsel[(size_t)(wrow0 + row) * 192 + kb + kc4]);
            u16x4 bvv;
            bvv[0] = f2bf(v.x); bvv[1] = f2bf(v.y); bvv[2] = f2bf(v.z); bvv[3] = f2bf(v.w);
            int boff = (kc4 * 2) ^ ((row & 3) << 4);
            *reinterpret_cast<u16x4*>(Bs + row * 192 + boff) = bvv;
        }
        __syncthreads();

#pragma unroll
        for (int ks = 0; ks < 3; ks++) {
            s16x8 af[4], bf[3];
#pragma unroll
            for (int i = 0; i < 4; i++) {
                int row = wm * 64 + i * 16 + lr;
                int off = (ks * 64 + lk * 16) ^ ((row & 3) << 4);
                af[i] = *reinterpret_cast<const s16x8*>(As + row * 192 + off);
            }
#pragma unroll
            for (int j = 0; j < 3; j++) {
                int row = wn * 48 + j * 16 + lr;
                int off = (ks * 64 + lk * 16) ^ ((row & 3) << 4);
                bf[j] = *reinterpret_cast<const s16x8*>(Bs + row * 192 + off);
            }
#pragma unroll
            for (int i = 0; i < 4; i++)
#pragma unroll
                for (int j = 0; j < 3; j++)
                    acc[i][j] = __builtin_amdgcn_mfma_f32_16x16x32_bf16(
                        af[i], bf[j], acc[i][j], 0, 0, 0);
        }
        __syncthreads();
    }

#pragma unroll
    for (int j = 0; j < 3; j++) {
        int bcol = gn0 + wn * 48 + j * 16 + lr;
        float bv = (EPI == 3 && bcol >= 192) ? b1[bcol - 192] : b0[bcol];
        void* dst = C0v;
        int oc = bcol;
        if ((EPI == 2 || EPI == 3) && bcol >= 192) { dst = C1v; oc = bcol - 192; }
#pragma unroll
        for (int i = 0; i < 4; i++) {
            int rbase = gm0 + wm * 64 + i * 16 + lk * 4;
#pragma unroll
            for (int r = 0; r < 4; r++) {
                float v = acc[i][j][r] + bv;
                if (EPI == 1) v = 0.5f * v * (1.f + erff(v * 0.70710678118654752440f));
                size_t idx = (size_t)(rbase + r) * 192 + oc;
                if (OUTBF) ((unsigned short*)dst)[idx] = f2bf(v);
                else       ((float*)dst)[idx] = v;
            }
        }
    }
}

// ---------------------------------------------------------------------------
// Fused window attention, key-split, bf16 LDS: block = (bb,t,m), 768 thr = 12
// waves. Wave w: head h = w>>1, keys [(w&1)*32 .. +32). K/V/mask/rpb stored
// bf16 in one LDS pool; unpack to f32 in registers. Mask row preloaded into
// 16 u32 regs (4 ds_read_b128) instead of 32 per-key ds_read_u16.
// launch_bounds (768,1) ONLY — anything higher spills (r8/r9).
// smem (u16 idx): K @0 [64*192], V @12288, mask @24576 [64 rows * 72],
//                 rpbT @29184 [6*226], exm(f32) @30544, exl(f32) @32080.
// ---------------------------------------------------------------------------
__global__ __launch_bounds__(768, 1)
void winattn_kernel(const float* __restrict__ qbuf,
                    const unsigned short* __restrict__ kbuf,
                    const unsigned short* __restrict__ vbuf,
                    const float* __restrict__ mask,
                    const float* __restrict__ rpbt, unsigned short* __restrict__ xp)
{
    __shared__ __align__(16) unsigned short smem[33616];   // 67232 B
    float* exm = (float*)(smem + 30544);
    float* exl = (float*)(smem + 32080);
    unsigned* obuf = (unsigned*)smem;                      // alias K/V after PV
    const int tid = threadIdx.x;
    const int bid = blockIdx.x;            // bb*16 + t*4 + m
    const int bb = bid >> 4;
    const int t = (bid >> 2) & 3;
    const int m = bid & 3;
    const int w = tid >> 6;
    const int h = w >> 1;
    const int lane = tid & 63;

    const int kvbase = (bb * 4 + m) * 12288;
#pragma unroll
    for (int it = 0; it < 2; it++) {
        int i8 = tid + it * 768;           // 0..1535
        *reinterpret_cast<u16x8*>(&smem[i8 * 8]) =
            *reinterpret_cast<const u16x8*>(&kbuf[kvbase + i8 * 8]);
        *reinterpret_cast<u16x8*>(&smem[12288 + i8 * 8]) =
            *reinterpret_cast<const u16x8*>(&vbuf[kvbase + i8 * 8]);
    }
    const int widx = bb & 63;
    for (int f = tid; f < 2048; f += 768) {
        int q = f >> 5, ee = (f & 31) * 2;
        float2 mv = *reinterpret_cast<const float2*>(&mask[widx * 4096 + q * 64 + ee]);
        unsigned pk = (unsigned)f2bf(mv.x) | ((unsigned)f2bf(mv.y) << 16);
        *reinterpret_cast<unsigned*>(&smem[24576 + q * 72 + ee]) = pk;
    }
    for (int f = tid; f < 1350; f += 768) {
        int hh = f / 225, rr = f - hh * 225;
        smem[29184 + hh * 226 + rr] = f2bf(rpbt[rr * 6 + hh]);
    }

    float qreg[32];
    const int qbase = ((bb * 4 + t) * 64 + lane) * 192 + h * 32;
#pragma unroll
    for (int j = 0; j < 8; j++) {
        float4 v = *reinterpret_cast<const float4*>(&qbuf[qbase + j * 4]);
        qreg[4 * j] = v.x; qreg[4 * j + 1] = v.y;
        qreg[4 * j + 2] = v.z; qreg[4 * j + 3] = v.w;
    }
    __syncthreads();

    const float scale = 0.17677669529663688110f;  // 1/sqrt(32)
    const int ni = lane >> 3, nj = lane & 7;
    const int e0 = (w & 1) << 5;

    // preload this lane's mask row half (32 bf16 = 64 B = 4 x b128)
    u32x4 mrow[4];
#pragma unroll
    for (int i = 0; i < 4; i++)
        mrow[i] = *reinterpret_cast<const u32x4*>(&smem[24576 + lane * 72 + e0 + i * 8]);

    float s[32];
#pragma unroll
    for (int ee = 0; ee < 32; ee++) {
        int e = e0 + ee;
        const u32x4* kr = reinterpret_cast<const u32x4*>(&smem[e * 192 + h * 32]);
        u32x4 k0 = kr[0], k1 = kr[1], k2 = kr[2], k3 = kr[3];
        float d0 = 0.f, d1 = 0.f;
        u32x4 kk[4] = {k0, k1, k2, k3};
#pragma unroll
        for (int v4 = 0; v4 < 4; v4++)
#pragma unroll
            for (int jj = 0; jj < 4; jj++) {
                unsigned wv = kk[v4][jj];
                int b = v4 * 8 + jj * 2;
                d0 += qreg[b] * bflo(wv);
                d1 += qreg[b + 1] * bfhi(wv);
            }
        int ridx = (ni - (e >> 3) + 7) * 15 + (nj - (e & 7) + 7);
        unsigned mw = mrow[ee >> 3][(ee >> 1) & 3];
        float mval = (ee & 1) ? bfhi(mw) : bflo(mw);
        s[ee] = (d0 + d1) * scale + bf2f(smem[29184 + h * 226 + ridx]) + mval;
    }
    float mrun = s[0];
#pragma unroll
    for (int ee = 1; ee < 32; ee++) mrun = fmaxf(mrun, s[ee]);
    float lrun = 0.f;
#pragma unroll
    for (int ee = 0; ee < 32; ee++) { s[ee] = __expf(s[ee] - mrun); lrun += s[ee]; }

    float o[32];
#pragma unroll
    for (int d = 0; d < 32; d++) o[d] = 0.f;
#pragma unroll
    for (int ee = 0; ee < 32; ee++) {
        float p = s[ee];
        const u32x4* vr = reinterpret_cast<const u32x4*>(&smem[12288 + (e0 + ee) * 192 + h * 32]);
        u32x4 v0 = vr[0], v1 = vr[1], v2 = vr[2], v3 = vr[3];
        u32x4 vv[4] = {v0, v1, v2, v3};
#pragma unroll
        for (int v4 = 0; v4 < 4; v4++)
#pragma unroll
            for (int jj = 0; jj < 4; jj++) {
                unsigned wv = vv[v4][jj];
                int b = v4 * 8 + jj * 2;
                o[b] += p * bflo(wv);
                o[b + 1] += p * bfhi(wv);
            }
    }

    // ---- pair merge: waves (2h, 2h+1); obuf aliases dead K/V region ----
    __syncthreads();
    exm[w * 64 + lane] = mrun;
    __syncthreads();
    float mo = exm[(w ^ 1) * 64 + lane];
    float mt = fmaxf(mrun, mo);
    float fs = __expf(mrun - mt);
    if (w & 1) {
        unsigned* ob = &obuf[h * 1088 + lane * 17];
#pragma unroll
        for (int j = 0; j < 16; j++) {
            unsigned lo = f2bf(fs * o[2 * j]);
            unsigned hi = f2bf(fs * o[2 * j + 1]);
            ob[j] = lo | (hi << 16);
        }
        exl[w * 64 + lane] = fs * lrun;
    }
    __syncthreads();
    if (!(w & 1)) {
        float lt = fs * lrun + exl[(w + 1) * 64 + lane];
        const float inv = 1.f / lt;
        const unsigned* ob = &obuf[h * 1088 + lane * 17];
        const int obase = bb * 196608 + m * 49152 + t * 12288 + h * 2048 + lane * 32;
#pragma unroll
        for (int j = 0; j < 8; j++) {
            unsigned p0 = ob[2 * j], p1 = ob[2 * j + 1];
            u16x4 v;
            v[0] = f2bf((fs * o[4 * j]     + bf2f((unsigned short)(p0 & 0xffff))) * inv);
            v[1] = f2bf((fs * o[4 * j + 1] + bf2f((unsigned short)(p0 >> 16))) * inv);
            v[2] = f2bf((fs * o[4 * j + 2] + bf2f((unsigned short)(p1 & 0xffff))) * inv);
            v[3] = f2bf((fs * o[4 * j + 3] + bf2f((unsigned short)(p1 >> 16))) * inv);
            *reinterpret_cast<u16x4*>(&xp[obase + j * 4]) = v;
        }
    }
}

// ---------------------------------------------------------------------------
// Pooling attention (r7 known-good f32-LDS version): block = (h, btl),
// 320 threads = 5 waves. Wave w handles key tiles {w, w+5} of 10 (32 keys)
// with private online softmax; partials merged via LDS.
// ---------------------------------------------------------------------------
__global__ __launch_bounds__(320)
void poolattn3_kernel(const unsigned short* __restrict__ kk,
                      const unsigned short* __restrict__ vv,
                      const float* __restrict__ qq, float* __restrict__ opool, int c0)
{
    __shared__ float ubuf[10560];      // union: K/V slots (w*2048) | sco (w*2112+q*33+d)
    __shared__ float scm[320], scl[320];
    const int tid = threadIdx.x;
    const int w = tid >> 6, lane = tid & 63;
    const int h = blockIdx.x, btl = blockIdx.y;
    const int bt = c0 + btl;
    float* Kf = ubuf + w * 2048;
    float* Vf = Kf + 1024;

    float qreg[32];
    const size_t qbase = (size_t)(bt * 64 + lane) * 192 + h * 32;
#pragma unroll
    for (int j = 0; j < 8; j++) {
        float4 v = *reinterpret_cast<const float4*>(&qq[qbase + j * 4]);
        qreg[4 * j] = v.x; qreg[4 * j + 1] = v.y;
        qreg[4 * j + 2] = v.z; qreg[4 * j + 3] = v.w;
    }
    const float scale = 0.17677669529663688110f;
    float mrun = -3.0e38f, lrun = 0.f;
    float o[32];
#pragma unroll
    for (int d = 0; d < 32; d++) o[d] = 0.f;

#pragma unroll
    for (int it = 0; it < 2; it++) {
        const int tt = w + it * 5;
        const unsigned short* ks = kk + (size_t)(btl * 320 + tt * 32) * 192 + h * 32;
        const unsigned short* vs = vv + (size_t)(btl * 320 + tt * 32) * 192 + h * 32;
#pragma unroll
        for (int ci = 0; ci < 2; ci++) {
            int idx = lane + ci * 64;          // 0..127
            int j = idx >> 2, q4 = (idx & 3) * 8;
            s16x8 kv8 = *reinterpret_cast<const s16x8*>(&ks[j * 192 + q4]);
            s16x8 vv8 = *reinterpret_cast<const s16x8*>(&vs[j * 192 + q4]);
            f32x4 lo, hi, vlo, vhi;
#pragma unroll
            for (int e = 0; e < 4; e++) {
                lo[e] = bf2f((unsigned short)kv8[e]);
                hi[e] = bf2f((unsigned short)kv8[e + 4]);
                vlo[e] = bf2f((unsigned short)vv8[e]);
                vhi[e] = bf2f((unsigned short)vv8[e + 4]);
            }
            *reinterpret_cast<f32x4*>(Kf + j * 32 + q4) = lo;
            *reinterpret_cast<f32x4*>(Kf + j * 32 + q4 + 4) = hi;
            *reinterpret_cast<f32x4*>(Vf + j * 32 + q4) = vlo;
            *reinterpret_cast<f32x4*>(Vf + j * 32 + q4 + 4) = vhi;
        }
        float s[32];
#pragma unroll
        for (int j = 0; j < 32; j++) {
            const float4* kr = reinterpret_cast<const float4*>(Kf + j * 32);
            float d0 = 0, d1 = 0, d2 = 0, d3 = 0;
#pragma unroll
            for (int q8 = 0; q8 < 8; q8++) {
                float4 k4 = kr[q8];
                d0 += qreg[q8 * 4] * k4.x;
                d1 += qreg[q8 * 4 + 1] * k4.y;
                d2 += qreg[q8 * 4 + 2] * k4.z;
                d3 += qreg[q8 * 4 + 3] * k4.w;
            }
            s[j] = (d0 + d1 + d2 + d3) * scale;
        }
        float mt = s[0];
#pragma unroll
        for (int j = 1; j < 32; j++) mt = fmaxf(mt, s[j]);
        float mnew = fmaxf(mrun, mt);
        float fct = __expf(mrun - mnew);
        lrun *= fct;
#pragma unroll
        for (int d = 0; d < 32; d++) o[d] *= fct;
#pragma unroll
        for (int j = 0; j < 32; j++) { float p = __expf(s[j] - mnew); lrun += p; s[j] = p; }
#pragma unroll
        for (int j = 0; j < 32; j++) {
            float p = s[j];
            const float4* vr = reinterpret_cast<const float4*>(Vf + j * 32);
#pragma unroll
            for (int d8 = 0; d8 < 8; d8++) {
                float4 v4 = vr[d8];
                o[d8 * 4] += p * v4.x; o[d8 * 4 + 1] += p * v4.y;
                o[d8 * 4 + 2] += p * v4.z; o[d8 * 4 + 3] += p * v4.w;
            }
        }
        mrun = mnew;
    }
    __syncthreads();                 // everyone done with K/V region
    scm[w * 64 + lane] = mrun;
    scl[w * 64 + lane] = lrun;
#pragma unroll
    for (int d = 0; d < 32; d++) ubuf[w * 2112 + lane * 33 + d] = o[d];
    __syncthreads();

    if (w == 0) {
        float m5 = scm[lane];
#pragma unroll
        for (int ww = 1; ww < 5; ww++) m5 = fmaxf(m5, scm[ww * 64 + lane]);
        float den = 0.f;
        float od[32];
#pragma unroll
        for (int d = 0; d < 32; d++) od[d] = 0.f;
#pragma unroll
        for (int ww = 0; ww < 5; ww++) {
            float f = __expf(scm[ww * 64 + lane] - m5);
            den += f * scl[ww * 64 + lane];
            const float* src = ubuf + ww * 2112 + lane * 33;
#pragma unroll
            for (int d = 0; d < 32; d++) od[d] += f * src[d];
        }
        const float inv = 1.f / den;
        const size_t ob = (size_t)(bt * 64 + lane) * 192 + h * 32;
#pragma unroll
        for (int j = 0; j < 8; j++) {
            float4 v;
            v.x = od[4 * j] * inv; v.y = od[4 * j + 1] * inv;
            v.z = od[4 * j + 2] * inv; v.w = od[4 * j + 3] * inv;
            *reinterpret_cast<float4*>(&opool[ob + j * 4]) = v;
        }
    }
}

extern "C" void kernel_launch(void* const* d_in, const int* in_sizes, int n_in,
                              void* d_out, int out_size, void* d_ws, size_t ws_size,
                              hipStream_t stream) {
    (void)in_sizes; (void)n_in; (void)out_size; (void)ws_size;
    const float* x      = (const float*)d_in[0];
    const float* x_kv   = (const float*)d_in[1];
    const float* mask   = (const float*)d_in[2];
    const float* rpbt   = (const float*)d_in[3];
    const float* q_w    = (const float*)d_in[4];
    const float* q_b    = (const float*)d_in[5];
    const float* kv_w   = (const float*)d_in[6];
    const float* kv_b   = (const float*)d_in[7];
    const float* pos    = (const float*)d_in[8];
    const float* pq_w   = (const float*)d_in[9];
    const float* pq_b   = (const float*)d_in[10];
    const float* pk_w   = (const float*)d_in[11];
    const float* pk_b   = (const float*)d_in[12];
    const float* pv_w   = (const float*)d_in[13];
    const float* pv_b   = (const float*)d_in[14];
    const float* po_w   = (const float*)d_in[15];
    const float* po_b   = (const float*)d_in[16];
    const float* proj_w = (const float*)d_in[17];
    const float* proj_b = (const float*)d_in[18];
    float* out = (float*)d_out;
    char* ws = (char*)d_ws;

    float*          qbuf = (float*)(ws);                       // 24 MB
    unsigned short* xp   = (unsigned short*)(ws + 25165824u);  // 48 MB bf16
    unsigned short* kbuf = (unsigned short*)(ws + 75497472u);  // 12 MB bf16
    unsigned short* vbuf = (unsigned short*)(ws + 88080384u);  // 12 MB bf16
    float*          qq   = qbuf;
    unsigned short* kkc  = (unsigned short*)(ws + 75497472u);  // 31.5 MB / chunk
    unsigned short* vvc  = (unsigned short*)(ws + 106954752u); // 31.5 MB / chunk
    float*          opo  = (float*)(ws + 75497472u);           // after pooling
    float*          opool = out;                               // d_out as scratch

    dim3 blk(256);
    // q = x @ q_w^T + q_b
    mgemm_kernel<0, 0, 0><<<dim3(256, 2), blk, 0, stream>>>(
        x, nullptr, nullptr, q_w, nullptr, q_b, nullptr, qbuf, nullptr, 0);
    // k,v = x_kv @ kv_w^T + kv_b  (split at oc 192, bf16 out)
    mgemm_kernel<0, 2, 1><<<dim3(256, 4), blk, 0, stream>>>(
        x_kv, nullptr, nullptr, kv_w, nullptr, kv_b, nullptr, kbuf, vbuf, 0);
    winattn_kernel<<<2048, 768, 0, stream>>>(qbuf, kbuf, vbuf, mask, rpbt, xp);
    // qq = (mean_m xp + pos) @ pq_w^T + pq_b
    mgemm_kernel<1, 0, 0><<<dim3(256, 2), blk, 0, stream>>>(
        nullptr, xp, pos, pq_w, nullptr, pq_b, nullptr, qq, nullptr, 0);
    // pooling in 2 chunks of 256 bt
    for (int c0 = 0; c0 < 512; c0 += 256) {
        mgemm_kernel<2, 3, 1><<<dim3(640, 4), blk, 0, stream>>>(
            nullptr, xp, pos, pk_w, pv_w, pk_b, pv_b, kkc, vvc, c0);
        poolattn3_kernel<<<dim3(6, 256), 320, 0, stream>>>(kkc, vvc, qq, opool, c0);
    }
    // opo = gelu(opool @ po_w^T + po_b); out = opo @ proj_w^T + proj_b
    mgemm_kernel<0, 1, 0><<<dim3(256, 2), blk, 0, stream>>>(
        opool, nullptr, nullptr, po_w, nullptr, po_b, nullptr, opo, nullptr, 0);
    mgemm_kernel<0, 0, 0><<<dim3(256, 2), blk, 0, stream>>>(
        opo, nullptr, nullptr, proj_w, nullptr, proj_b, nullptr, out, nullptr, 0);
}

// Round 11
// 1289.316 us; speedup vs baseline: 2.1646x; 1.0464x over previous
//
#include <hip/hip_runtime.h>
#include <math.h>

// ---------------------------------------------------------------------------
// MultiReferenceWindowAttention — bf16-MFMA GEMMs + attention.
// B_=128, T=4, M=4, N=64, C=192, nH=6, hd=32, BT=512
// Workspace (<= proven 177,340,416 B):
//   qbuf f32  @ 0      (24 MB)  q -> later qq
//   xp  bf16  @ 24 MB  (48 MB)
//   kbuf bf16 @ 72 MB  (12 MB)  k -> later kk-chunk(bf16) -> later opo
//   vbuf bf16 @ 84 MB  (12 MB)  v
//   kk bf16 @ 72 MB (31.5 MB/chunk), vv bf16 @ 102 MB (31.5 MB/chunk)
// d_out doubles as opool scratch (fully rewritten by final GEMM).
//
// OCCUPANCY/SPILL LESSON (r7..r10): hipcc derives its occupancy target from
// LDS size. If LDS fits 2 blocks/CU (<80 KB), it caps VGPR at ~84 and our
// ~100-reg attention waves spill to scratch (r9/r10: 2.9 GB traffic, 3.8x
// slower). Fix: pad LDS above 80 KB to force 1 block/CU -> VGPR ceiling ~168.
// Also keep unpack temps streamed (one u32x4 live at a time), never bulk
// arrays, so live state stays ~90.
// ---------------------------------------------------------------------------

typedef float f32x4 __attribute__((ext_vector_type(4)));
typedef short s16x8 __attribute__((ext_vector_type(8)));
typedef unsigned short u16x4 __attribute__((ext_vector_type(4)));
typedef unsigned short u16x8 __attribute__((ext_vector_type(8)));
typedef unsigned u32x4 __attribute__((ext_vector_type(4)));

__device__ __forceinline__ unsigned short f2bf(float f) {
    union { float f; unsigned u; } c; c.f = f;
    return (unsigned short)((c.u + 0x7fffu + ((c.u >> 16) & 1u)) >> 16);
}
__device__ __forceinline__ float bf2f(unsigned short h) {
    union { unsigned u; float f; } c; c.u = ((unsigned)h) << 16;
    return c.f;
}
__device__ __forceinline__ float bflo(unsigned w) {   // low bf16 of packed u32
    union { unsigned u; float f; } c; c.u = w << 16;
    return c.f;
}
__device__ __forceinline__ float bfhi(unsigned w) {   // high bf16 of packed u32
    union { unsigned u; float f; } c; c.u = w & 0xffff0000u;
    return c.f;
}

// ---------------------------------------------------------------------------
// MFMA bf16 GEMM:  C[row, oc] = sum_k Arow[k] * W[oc][k] + bias[oc]
// Block tile 128 rows x 96 oc, K=192 staged in 2 halves of 96.
// SRC: 0 = A plain f32 rows; 1 = mean_m xp(bf16) + pos; 2 = seq rows from xp.
// EPI: 0 plain, 1 exact gelu, 2 split oc@192 -> C0/C1 (b0 len 384),
//      3 split oc@192 -> C0 (W0,b0) / C1 (W1,b1)
// OUTBF: 0 = f32 out, 1 = bf16 out.
// ---------------------------------------------------------------------------
template <int SRC, int EPI, int OUTBF>
__global__ __launch_bounds__(256, 3)
void mgemm_kernel(const float* __restrict__ A, const unsigned short* __restrict__ Axp,
                  const float* __restrict__ pos,
                  const float* __restrict__ W0, const float* __restrict__ W1,
                  const float* __restrict__ b0, const float* __restrict__ b1,
                  void* __restrict__ C0v, void* __restrict__ C1v, int c0)
{
    __shared__ __align__(16) char As[128 * 192];   // 24 KB bf16 [row][k(96)]
    __shared__ __align__(16) char Bs[96 * 192];    // 18 KB bf16 [oc][k(96)]
    const int tid = threadIdx.x;
    const int gm0 = blockIdx.x * 128;
    const int gn0 = blockIdx.y * 96;
    const int wid = tid >> 6;
    const int wm = wid >> 1, wn = wid & 1;
    const int lane = tid & 63;
    const int lr = lane & 15;
    const int lk = lane >> 4;

    const bool hiN = (gn0 >= 192);
    const float* Wsel = (EPI == 3 && hiN) ? W1 : W0;
    const int wrow0 = (EPI == 3 && hiN) ? (gn0 - 192) : gn0;

    f32x4 acc[4][3];
#pragma unroll
    for (int i = 0; i < 4; i++)
#pragma unroll
        for (int j = 0; j < 3; j++) acc[i][j] = (f32x4){0.f, 0.f, 0.f, 0.f};

    for (int kb = 0; kb < 192; kb += 96) {
#pragma unroll
        for (int it = 0; it < 12; it++) {
            int f4 = tid + it * 256;
            int row = f4 / 24;
            int kc4 = (f4 - row * 24) * 4;
            float av[4];
            if (SRC == 0) {
                float4 v = *reinterpret_cast<const float4*>(
                    &A[(size_t)(gm0 + row) * 192 + kb + kc4]);
                av[0] = v.x; av[1] = v.y; av[2] = v.z; av[3] = v.w;
            } else {
                int g = gm0 + row;
                int bt, tok;
                if (SRC == 1) { bt = g >> 6; tok = g & 63; }
                else { bt = g / 320; tok = g - bt * 320; bt += c0; }
                int n = tok & 63;
                int kcol = kb + kc4;
                float4 p4 = *reinterpret_cast<const float4*>(&pos[n * 192 + kcol]);
                float pv[4] = {p4.x, p4.y, p4.z, p4.w};
                if (SRC == 2 && tok >= 64) {
                    int mm = (tok >> 6) - 1;
                    u16x4 a = *reinterpret_cast<const u16x4*>(
                        &Axp[(size_t)bt * 49152 + mm * 12288 + n * 192 + kcol]);
#pragma unroll
                    for (int jj = 0; jj < 4; jj++) av[jj] = bf2f(a[jj]) + pv[jj];
                } else {
                    size_t xb = (size_t)bt * 49152 + n * 192 + kcol;
                    u16x4 a0 = *reinterpret_cast<const u16x4*>(&Axp[xb]);
                    u16x4 a1 = *reinterpret_cast<const u16x4*>(&Axp[xb + 12288]);
                    u16x4 a2 = *reinterpret_cast<const u16x4*>(&Axp[xb + 24576]);
                    u16x4 a3 = *reinterpret_cast<const u16x4*>(&Axp[xb + 36864]);
#pragma unroll
                    for (int jj = 0; jj < 4; jj++)
                        av[jj] = 0.25f * (bf2f(a0[jj]) + bf2f(a1[jj]) +
                                          bf2f(a2[jj]) + bf2f(a3[jj])) + pv[jj];
                }
            }
            u16x4 bvv;
#pragma unroll
            for (int jj = 0; jj < 4; jj++) bvv[jj] = f2bf(av[jj]);
            int boff = (kc4 * 2) ^ ((row & 3) << 4);
            *reinterpret_cast<u16x4*>(As + row * 192 + boff) = bvv;
        }
#pragma unroll
        for (int it = 0; it < 9; it++) {
            int f4 = tid + it * 256;
            int row = f4 / 24;
            int kc4 = (f4 - row * 24) * 4;
            float4 v = *reinterpret_cast<const float4*>(
                &Wsel[(size_t)(wrow0 + row) * 192 + kb + kc4]);
            u16x4 bvv;
            bvv[0] = f2bf(v.x); bvv[1] = f2bf(v.y); bvv[2] = f2bf(v.z); bvv[3] = f2bf(v.w);
            int boff = (kc4 * 2) ^ ((row & 3) << 4);
            *reinterpret_cast<u16x4*>(Bs + row * 192 + boff) = bvv;
        }
        __syncthreads();

#pragma unroll
        for (int ks = 0; ks < 3; ks++) {
            s16x8 af[4], bf[3];
#pragma unroll
            for (int i = 0; i < 4; i++) {
                int row = wm * 64 + i * 16 + lr;
                int off = (ks * 64 + lk * 16) ^ ((row & 3) << 4);
                af[i] = *reinterpret_cast<const s16x8*>(As + row * 192 + off);
            }
#pragma unroll
            for (int j = 0; j < 3; j++) {
                int row = wn * 48 + j * 16 + lr;
                int off = (ks * 64 + lk * 16) ^ ((row & 3) << 4);
                bf[j] = *reinterpret_cast<const s16x8*>(Bs + row * 192 + off);
            }
#pragma unroll
            for (int i = 0; i < 4; i++)
#pragma unroll
                for (int j = 0; j < 3; j++)
                    acc[i][j] = __builtin_amdgcn_mfma_f32_16x16x32_bf16(
                        af[i], bf[j], acc[i][j], 0, 0, 0);
        }
        __syncthreads();
    }

#pragma unroll
    for (int j = 0; j < 3; j++) {
        int bcol = gn0 + wn * 48 + j * 16 + lr;
        float bv = (EPI == 3 && bcol >= 192) ? b1[bcol - 192] : b0[bcol];
        void* dst = C0v;
        int oc = bcol;
        if ((EPI == 2 || EPI == 3) && bcol >= 192) { dst = C1v; oc = bcol - 192; }
#pragma unroll
        for (int i = 0; i < 4; i++) {
            int rbase = gm0 + wm * 64 + i * 16 + lk * 4;
#pragma unroll
            for (int r = 0; r < 4; r++) {
                float v = acc[i][j][r] + bv;
                if (EPI == 1) v = 0.5f * v * (1.f + erff(v * 0.70710678118654752440f));
                size_t idx = (size_t)(rbase + r) * 192 + oc;
                if (OUTBF) ((unsigned short*)dst)[idx] = f2bf(v);
                else       ((float*)dst)[idx] = v;
            }
        }
    }
}

// ---------------------------------------------------------------------------
// Fused window attention, key-split, bf16 LDS: block = (bb,t,m), 768 thr = 12
// waves. Wave w: head h = w>>1, keys [(w&1)*32 .. +32). K/V/mask/rpb stored
// bf16 in LDS; unpack to f32 in registers, ONE u32x4 live at a time.
// LDS padded to 84 KB: forces 1 block/CU so hipcc's occupancy heuristic
// allows ~168 VGPR (no scratch spill — see header note).
// smem (u16 idx): K @0 [64*192], V @12288, mask @24576 [64 rows * 72],
//                 rpbT @29184 [6*226], exm(f32) @30544, exl(f32) @32080.
// ---------------------------------------------------------------------------
__global__ __launch_bounds__(768, 1)
void winattn_kernel(const float* __restrict__ qbuf,
                    const unsigned short* __restrict__ kbuf,
                    const unsigned short* __restrict__ vbuf,
                    const float* __restrict__ mask,
                    const float* __restrict__ rpbt, unsigned short* __restrict__ xp)
{
    __shared__ __align__(16) unsigned short smem[43008];   // 86016 B (padded)
    float* exm = (float*)(smem + 30544);
    float* exl = (float*)(smem + 32080);
    unsigned* obuf = (unsigned*)smem;                      // alias K/V after PV
    const int tid = threadIdx.x;
    const int bid = blockIdx.x;            // bb*16 + t*4 + m
    const int bb = bid >> 4;
    const int t = (bid >> 2) & 3;
    const int m = bid & 3;
    const int w = tid >> 6;
    const int h = w >> 1;
    const int lane = tid & 63;

    const int kvbase = (bb * 4 + m) * 12288;
#pragma unroll
    for (int it = 0; it < 2; it++) {
        int i8 = tid + it * 768;           // 0..1535
        *reinterpret_cast<u16x8*>(&smem[i8 * 8]) =
            *reinterpret_cast<const u16x8*>(&kbuf[kvbase + i8 * 8]);
        *reinterpret_cast<u16x8*>(&smem[12288 + i8 * 8]) =
            *reinterpret_cast<const u16x8*>(&vbuf[kvbase + i8 * 8]);
    }
    const int widx = bb & 63;
    for (int f = tid; f < 2048; f += 768) {
        int q = f >> 5, ee = (f & 31) * 2;
        float2 mv = *reinterpret_cast<const float2*>(&mask[widx * 4096 + q * 64 + ee]);
        unsigned pk = (unsigned)f2bf(mv.x) | ((unsigned)f2bf(mv.y) << 16);
        *reinterpret_cast<unsigned*>(&smem[24576 + q * 72 + ee]) = pk;
    }
    for (int f = tid; f < 1350; f += 768) {
        int hh = f / 225, rr = f - hh * 225;
        smem[29184 + hh * 226 + rr] = f2bf(rpbt[rr * 6 + hh]);
    }

    float qreg[32];
    const int qbase = ((bb * 4 + t) * 64 + lane) * 192 + h * 32;
#pragma unroll
    for (int j = 0; j < 8; j++) {
        float4 v = *reinterpret_cast<const float4*>(&qbuf[qbase + j * 4]);
        qreg[4 * j] = v.x; qreg[4 * j + 1] = v.y;
        qreg[4 * j + 2] = v.z; qreg[4 * j + 3] = v.w;
    }
    __syncthreads();

    const float scale = 0.17677669529663688110f;  // 1/sqrt(32)
    const int ni = lane >> 3, nj = lane & 7;
    const int e0 = (w & 1) << 5;

    // preload this lane's mask row half (32 bf16 = 64 B = 4 x b128)
    u32x4 mrow[4];
#pragma unroll
    for (int i = 0; i < 4; i++)
        mrow[i] = *reinterpret_cast<const u32x4*>(&smem[24576 + lane * 72 + e0 + i * 8]);

    float s[32];
#pragma unroll
    for (int ee = 0; ee < 32; ee++) {
        int e = e0 + ee;
        const u32x4* kr = reinterpret_cast<const u32x4*>(&smem[e * 192 + h * 32]);
        float d0 = 0.f, d1 = 0.f;
#pragma unroll
        for (int v4 = 0; v4 < 4; v4++) {
            u32x4 kw = kr[v4];             // one u32x4 live at a time
#pragma unroll
            for (int jj = 0; jj < 4; jj++) {
                unsigned wv = kw[jj];
                int b = v4 * 8 + jj * 2;
                d0 += qreg[b] * bflo(wv);
                d1 += qreg[b + 1] * bfhi(wv);
            }
        }
        int ridx = (ni - (e >> 3) + 7) * 15 + (nj - (e & 7) + 7);
        unsigned mw = mrow[ee >> 3][(ee >> 1) & 3];
        float mval = (ee & 1) ? bfhi(mw) : bflo(mw);
        s[ee] = (d0 + d1) * scale + bf2f(smem[29184 + h * 226 + ridx]) + mval;
    }
    float mrun = s[0];
#pragma unroll
    for (int ee = 1; ee < 32; ee++) mrun = fmaxf(mrun, s[ee]);
    float lrun = 0.f;
#pragma unroll
    for (int ee = 0; ee < 32; ee++) { s[ee] = __expf(s[ee] - mrun); lrun += s[ee]; }

    float o[32];
#pragma unroll
    for (int d = 0; d < 32; d++) o[d] = 0.f;
#pragma unroll
    for (int ee = 0; ee < 32; ee++) {
        float p = s[ee];
        const u32x4* vr = reinterpret_cast<const u32x4*>(&smem[12288 + (e0 + ee) * 192 + h * 32]);
#pragma unroll
        for (int v4 = 0; v4 < 4; v4++) {
            u32x4 vw = vr[v4];             // one u32x4 live at a time
#pragma unroll
            for (int jj = 0; jj < 4; jj++) {
                unsigned wv = vw[jj];
                int b = v4 * 8 + jj * 2;
                o[b] += p * bflo(wv);
                o[b + 1] += p * bfhi(wv);
            }
        }
    }

    // ---- pair merge: waves (2h, 2h+1); obuf aliases dead K/V region ----
    __syncthreads();
    exm[w * 64 + lane] = mrun;
    __syncthreads();
    float mo = exm[(w ^ 1) * 64 + lane];
    float mt = fmaxf(mrun, mo);
    float fs = __expf(mrun - mt);
    if (w & 1) {
        unsigned* ob = &obuf[h * 1088 + lane * 17];
#pragma unroll
        for (int j = 0; j < 16; j++) {
            unsigned lo = f2bf(fs * o[2 * j]);
            unsigned hi = f2bf(fs * o[2 * j + 1]);
            ob[j] = lo | (hi << 16);
        }
        exl[w * 64 + lane] = fs * lrun;
    }
    __syncthreads();
    if (!(w & 1)) {
        float lt = fs * lrun + exl[(w + 1) * 64 + lane];
        const float inv = 1.f / lt;
        const unsigned* ob = &obuf[h * 1088 + lane * 17];
        const int obase = bb * 196608 + m * 49152 + t * 12288 + h * 2048 + lane * 32;
#pragma unroll
        for (int j = 0; j < 8; j++) {
            unsigned p0 = ob[2 * j], p1 = ob[2 * j + 1];
            u16x4 v;
            v[0] = f2bf((fs * o[4 * j]     + bf2f((unsigned short)(p0 & 0xffff))) * inv);
            v[1] = f2bf((fs * o[4 * j + 1] + bf2f((unsigned short)(p0 >> 16))) * inv);
            v[2] = f2bf((fs * o[4 * j + 2] + bf2f((unsigned short)(p1 & 0xffff))) * inv);
            v[3] = f2bf((fs * o[4 * j + 3] + bf2f((unsigned short)(p1 >> 16))) * inv);
            *reinterpret_cast<u16x4*>(&xp[obase + j * 4]) = v;
        }
    }
}

// ---------------------------------------------------------------------------
// Pooling attention (r7 known-good f32-LDS version): block = (h, btl),
// 320 threads = 5 waves. Wave w handles key tiles {w, w+5} of 10 (32 keys)
// with private online softmax; partials merged via LDS.
// ---------------------------------------------------------------------------
__global__ __launch_bounds__(320)
void poolattn3_kernel(const unsigned short* __restrict__ kk,
                      const unsigned short* __restrict__ vv,
                      const float* __restrict__ qq, float* __restrict__ opool, int c0)
{
    __shared__ float ubuf[10560];      // union: K/V slots (w*2048) | sco (w*2112+q*33+d)
    __shared__ float scm[320], scl[320];
    const int tid = threadIdx.x;
    const int w = tid >> 6, lane = tid & 63;
    const int h = blockIdx.x, btl = blockIdx.y;
    const int bt = c0 + btl;
    float* Kf = ubuf + w * 2048;
    float* Vf = Kf + 1024;

    float qreg[32];
    const size_t qbase = (size_t)(bt * 64 + lane) * 192 + h * 32;
#pragma unroll
    for (int j = 0; j < 8; j++) {
        float4 v = *reinterpret_cast<const float4*>(&qq[qbase + j * 4]);
        qreg[4 * j] = v.x; qreg[4 * j + 1] = v.y;
        qreg[4 * j + 2] = v.z; qreg[4 * j + 3] = v.w;
    }
    const float scale = 0.17677669529663688110f;
    float mrun = -3.0e38f, lrun = 0.f;
    float o[32];
#pragma unroll
    for (int d = 0; d < 32; d++) o[d] = 0.f;

#pragma unroll
    for (int it = 0; it < 2; it++) {
        const int tt = w + it * 5;
        const unsigned short* ks = kk + (size_t)(btl * 320 + tt * 32) * 192 + h * 32;
        const unsigned short* vs = vv + (size_t)(btl * 320 + tt * 32) * 192 + h * 32;
#pragma unroll
        for (int ci = 0; ci < 2; ci++) {
            int idx = lane + ci * 64;          // 0..127
            int j = idx >> 2, q4 = (idx & 3) * 8;
            s16x8 kv8 = *reinterpret_cast<const s16x8*>(&ks[j * 192 + q4]);
            s16x8 vv8 = *reinterpret_cast<const s16x8*>(&vs[j * 192 + q4]);
            f32x4 lo, hi, vlo, vhi;
#pragma unroll
            for (int e = 0; e < 4; e++) {
                lo[e] = bf2f((unsigned short)kv8[e]);
                hi[e] = bf2f((unsigned short)kv8[e + 4]);
                vlo[e] = bf2f((unsigned short)vv8[e]);
                vhi[e] = bf2f((unsigned short)vv8[e + 4]);
            }
            *reinterpret_cast<f32x4*>(Kf + j * 32 + q4) = lo;
            *reinterpret_cast<f32x4*>(Kf + j * 32 + q4 + 4) = hi;
            *reinterpret_cast<f32x4*>(Vf + j * 32 + q4) = vlo;
            *reinterpret_cast<f32x4*>(Vf + j * 32 + q4 + 4) = vhi;
        }
        float s[32];
#pragma unroll
        for (int j = 0; j < 32; j++) {
            const float4* kr = reinterpret_cast<const float4*>(Kf + j * 32);
            float d0 = 0, d1 = 0, d2 = 0, d3 = 0;
#pragma unroll
            for (int q8 = 0; q8 < 8; q8++) {
                float4 k4 = kr[q8];
                d0 += qreg[q8 * 4] * k4.x;
                d1 += qreg[q8 * 4 + 1] * k4.y;
                d2 += qreg[q8 * 4 + 2] * k4.z;
                d3 += qreg[q8 * 4 + 3] * k4.w;
            }
            s[j] = (d0 + d1 + d2 + d3) * scale;
        }
        float mt = s[0];
#pragma unroll
        for (int j = 1; j < 32; j++) mt = fmaxf(mt, s[j]);
        float mnew = fmaxf(mrun, mt);
        float fct = __expf(mrun - mnew);
        lrun *= fct;
#pragma unroll
        for (int d = 0; d < 32; d++) o[d] *= fct;
#pragma unroll
        for (int j = 0; j < 32; j++) { float p = __expf(s[j] - mnew); lrun += p; s[j] = p; }
#pragma unroll
        for (int j = 0; j < 32; j++) {
            float p = s[j];
            const float4* vr = reinterpret_cast<const float4*>(Vf + j * 32);
#pragma unroll
            for (int d8 = 0; d8 < 8; d8++) {
                float4 v4 = vr[d8];
                o[d8 * 4] += p * v4.x; o[d8 * 4 + 1] += p * v4.y;
                o[d8 * 4 + 2] += p * v4.z; o[d8 * 4 + 3] += p * v4.w;
            }
        }
        mrun = mnew;
    }
    __syncthreads();                 // everyone done with K/V region
    scm[w * 64 + lane] = mrun;
    scl[w * 64 + lane] = lrun;
#pragma unroll
    for (int d = 0; d < 32; d++) ubuf[w * 2112 + lane * 33 + d] = o[d];
    __syncthreads();

    if (w == 0) {
        float m5 = scm[lane];
#pragma unroll
        for (int ww = 1; ww < 5; ww++) m5 = fmaxf(m5, scm[ww * 64 + lane]);
        float den = 0.f;
        float od[32];
#pragma unroll
        for (int d = 0; d < 32; d++) od[d] = 0.f;
#pragma unroll
        for (int ww = 0; ww < 5; ww++) {
            float f = __expf(scm[ww * 64 + lane] - m5);
            den += f * scl[ww * 64 + lane];
            const float* src = ubuf + ww * 2112 + lane * 33;
#pragma unroll
            for (int d = 0; d < 32; d++) od[d] += f * src[d];
        }
        const float inv = 1.f / den;
        const size_t ob = (size_t)(bt * 64 + lane) * 192 + h * 32;
#pragma unroll
        for (int j = 0; j < 8; j++) {
            float4 v;
            v.x = od[4 * j] * inv; v.y = od[4 * j + 1] * inv;
            v.z = od[4 * j + 2] * inv; v.w = od[4 * j + 3] * inv;
            *reinterpret_cast<float4*>(&opool[ob + j * 4]) = v;
        }
    }
}

extern "C" void kernel_launch(void* const* d_in, const int* in_sizes, int n_in,
                              void* d_out, int out_size, void* d_ws, size_t ws_size,
                              hipStream_t stream) {
    (void)in_sizes; (void)n_in; (void)out_size; (void)ws_size;
    const float* x      = (const float*)d_in[0];
    const float* x_kv   = (const float*)d_in[1];
    const float* mask   = (const float*)d_in[2];
    const float* rpbt   = (const float*)d_in[3];
    const float* q_w    = (const float*)d_in[4];
    const float* q_b    = (const float*)d_in[5];
    const float* kv_w   = (const float*)d_in[6];
    const float* kv_b   = (const float*)d_in[7];
    const float* pos    = (const float*)d_in[8];
    const float* pq_w   = (const float*)d_in[9];
    const float* pq_b   = (const float*)d_in[10];
    const float* pk_w   = (const float*)d_in[11];
    const float* pk_b   = (const float*)d_in[12];
    const float* pv_w   = (const float*)d_in[13];
    const float* pv_b   = (const float*)d_in[14];
    const float* po_w   = (const float*)d_in[15];
    const float* po_b   = (const float*)d_in[16];
    const float* proj_w = (const float*)d_in[17];
    const float* proj_b = (const float*)d_in[18];
    float* out = (float*)d_out;
    char* ws = (char*)d_ws;

    float*          qbuf = (float*)(ws);                       // 24 MB
    unsigned short* xp   = (unsigned short*)(ws + 25165824u);  // 48 MB bf16
    unsigned short* kbuf = (unsigned short*)(ws + 75497472u);  // 12 MB bf16
    unsigned short* vbuf = (unsigned short*)(ws + 88080384u);  // 12 MB bf16
    float*          qq   = qbuf;
    unsigned short* kkc  = (unsigned short*)(ws + 75497472u);  // 31.5 MB / chunk
    unsigned short* vvc  = (unsigned short*)(ws + 106954752u); // 31.5 MB / chunk
    float*          opo  = (float*)(ws + 75497472u);           // after pooling
    float*          opool = out;                               // d_out as scratch

    dim3 blk(256);
    // q = x @ q_w^T + q_b
    mgemm_kernel<0, 0, 0><<<dim3(256, 2), blk, 0, stream>>>(
        x, nullptr, nullptr, q_w, nullptr, q_b, nullptr, qbuf, nullptr, 0);
    // k,v = x_kv @ kv_w^T + kv_b  (split at oc 192, bf16 out)
    mgemm_kernel<0, 2, 1><<<dim3(256, 4), blk, 0, stream>>>(
        x_kv, nullptr, nullptr, kv_w, nullptr, kv_b, nullptr, kbuf, vbuf, 0);
    winattn_kernel<<<2048, 768, 0, stream>>>(qbuf, kbuf, vbuf, mask, rpbt, xp);
    // qq = (mean_m xp + pos) @ pq_w^T + pq_b
    mgemm_kernel<1, 0, 0><<<dim3(256, 2), blk, 0, stream>>>(
        nullptr, xp, pos, pq_w, nullptr, pq_b, nullptr, qq, nullptr, 0);
    // pooling in 2 chunks of 256 bt
    for (int c0 = 0; c0 < 512; c0 += 256) {
        mgemm_kernel<2, 3, 1><<<dim3(640, 4), blk, 0, stream>>>(
            nullptr, xp, pos, pk_w, pv_w, pk_b, pv_b, kkc, vvc, c0);
        poolattn3_kernel<<<dim3(6, 256), 320, 0, stream>>>(kkc, vvc, qq, opool, c0);
    }
    // opo = gelu(opool @ po_w^T + po_b); out = opo @ proj_w^T + proj_b
    mgemm_kernel<0, 1, 0><<<dim3(256, 2), blk, 0, stream>>>(
        opool, nullptr, nullptr, po_w, nullptr, po_b, nullptr, opo, nullptr, 0);
    mgemm_kernel<0, 0, 0><<<dim3(256, 2), blk, 0, stream>>>(
        opo, nullptr, nullptr, proj_w, nullptr, proj_b, nullptr, out, nullptr, 0);
}